// Round 12
// baseline (333.845 us; speedup 1.0000x reference)
//
#include <hip/hip_runtime.h>
#include <cstdint>
#include <cstddef>

// ---------------------------------------------------------------------------
// GCN forward, MFMA edition:
//   bucketed graph preprocessing (NO scattered global atomics anywhere):
//     bcount -> bscan -> scatter2 -> bucket_dst (ind+rowp+csr) ->
//     bucket_src (outd) -> norms
//   -> WF=projW@W1mid -> WT in MFMA FRAGMENT ORDER, hi/lo bf16
//   -> h1 = cs*(x@W1+cb) [split-bf16 3-term MFMA] -> agg1 -> y=relu(...)
//   -> h2 = cs*(y@W2) -> aggs2 -> out
// Split trick: a = a_hi + a_lo (bf16 trunc + bf16 residual);
// D = ahi*bhi + alo*bhi + ahi*blo -> only O(2^-17) rel. terms dropped.
// R11 lesson (the pin on 3 identical ~116us k_h1 variants): __syncthreads
// on gfx950 emits s_waitcnt vmcnt(0) before s_barrier -> EVERY per-step
// barrier drains ALL outstanding global loads; software prefetch of any
// depth dies at the first barrier. FIX (T3/T4): raw s_barrier + counted
// vmcnt(4) (never 0 mid-loop) + global_load_lds(16B) for B staging.
// Issue order per step: B(t+1) glds FIRST, then A(t+2) reg loads; queue at
// each wait = [A(t),B(t),A(t+1)] -> vmcnt(4) completes A(t)+B(t), keeps
// A(t+1) in flight ACROSS the barrier. sched_barrier(0) pins issue order
// (vmcnt counts machine order) and fences ds_read hoisting (rule #18).
// R9 lesson: B must be LDS-shared per-block, lockstep (L1 thrash otherwise).
// R6/R7 lesson: scattered 4B atomics across XCD L2s = ~64B writeback each;
// bucket so each 1024-node range is built by ONE block in LDS.
// R4 lesson: never cap VGPRs below acc needs (spill -> scratch traffic).
// ---------------------------------------------------------------------------

typedef short short8 __attribute__((ext_vector_type(8)));
typedef float f32x4 __attribute__((ext_vector_type(4)));

__device__ __forceinline__ unsigned short f2bf(float f) {
    unsigned u = __float_as_uint(f);
    u += 0x7fff + ((u >> 16) & 1);   // RNE
    return (unsigned short)(u >> 16);
}
__device__ __forceinline__ float bf2f(unsigned short s) {
    return __uint_as_float(((unsigned)s) << 16);
}

__device__ __forceinline__ void split_f4(float4 a, float4 b, short8& hv, short8& lv) {
    float f[8] = {a.x, a.y, a.z, a.w, b.x, b.y, b.z, b.w};
#pragma unroll
    for (int i = 0; i < 8; ++i) {
        unsigned u = __float_as_uint(f[i]);
        hv[i] = (short)(u >> 16);
        float r = f[i] - __uint_as_float(u & 0xffff0000u);
        lv[i] = (short)(__float_as_uint(r) >> 16);
    }
}

// async global->LDS, 16B per lane; LDS dest must be linear in lane order.
__device__ __forceinline__ void glds16(const unsigned short* g, short* l) {
    __builtin_amdgcn_global_load_lds(
        (const __attribute__((address_space(1))) unsigned int*)g,
        (__attribute__((address_space(3))) unsigned int*)l, 16, 0, 0);
}

// ---- bucket preprocessing (buckets = 1024-node ranges, nb <= 128) ----

__global__ __launch_bounds__(256) void k_bcount(
    const int* __restrict__ src, const int* __restrict__ dst, int E,
    int* __restrict__ dcount, int* __restrict__ scount)
{
    __shared__ int dh[128], sh_[128];
    int t = threadIdx.x;
    if (t < 128) { dh[t] = 0; sh_[t] = 0; }
    __syncthreads();
    int e0 = blockIdx.x * 4096;
#pragma unroll
    for (int i = 0; i < 16; ++i) {
        int idx = e0 + t + i * 256;
        if (idx < E) {
            atomicAdd(&dh[dst[idx] >> 10], 1);
            atomicAdd(&sh_[src[idx] >> 10], 1);
        }
    }
    __syncthreads();
    if (t < 128) {
        if (dh[t]) atomicAdd(&dcount[t], dh[t]);
        if (sh_[t]) atomicAdd(&scount[t], sh_[t]);
    }
}

__global__ __launch_bounds__(128) void k_bscan(
    const int* __restrict__ dcount, const int* __restrict__ scount, int nb,
    int E, int* __restrict__ dboff, int* __restrict__ sboff,
    int* __restrict__ dcur, int* __restrict__ scur,
    int* __restrict__ rowp, int N)
{
    __shared__ int sh[128];
    int t = threadIdx.x;
    int v = (t < nb) ? dcount[t] : 0;
    sh[t] = v;
    __syncthreads();
    for (int off = 1; off < 128; off <<= 1) {
        int x = (t >= off) ? sh[t - off] : 0;
        __syncthreads();
        sh[t] += x;
        __syncthreads();
    }
    if (t < nb) { int e = sh[t] - v; dboff[t] = e; dcur[t] = e; }
    __syncthreads();
    int v2 = (t < nb) ? scount[t] : 0;
    sh[t] = v2;
    __syncthreads();
    for (int off = 1; off < 128; off <<= 1) {
        int x = (t >= off) ? sh[t - off] : 0;
        __syncthreads();
        sh[t] += x;
        __syncthreads();
    }
    if (t < nb) { int e = sh[t] - v2; sboff[t] = e; scur[t] = e; }
    if (t == 0) rowp[N] = E;
}

__global__ __launch_bounds__(256) void k_scatter2(
    const int* __restrict__ src, const int* __restrict__ dst, int E,
    int* __restrict__ dcur, int* __restrict__ scur,
    unsigned* __restrict__ ebuf, unsigned short* __restrict__ sbuf, int nb)
{
    __shared__ int dh[128], dbase[128], sh_[128], sbase[128];
    int t = threadIdx.x;
    int e0 = blockIdx.x * 4096;
    if (t < 128) { dh[t] = 0; sh_[t] = 0; }
    __syncthreads();
    int s_[16], d_[16];
#pragma unroll
    for (int i = 0; i < 16; ++i) {
        int idx = e0 + t + i * 256;
        if (idx < E) {
            s_[i] = src[idx];
            d_[i] = dst[idx];
            atomicAdd(&dh[d_[i] >> 10], 1);
            atomicAdd(&sh_[s_[i] >> 10], 1);
        } else d_[i] = -1;
    }
    __syncthreads();
    if (t < nb) {
        if (dh[t]) dbase[t] = atomicAdd(&dcur[t], dh[t]);
        if (sh_[t]) sbase[t] = atomicAdd(&scur[t], sh_[t]);
    }
    __syncthreads();
    if (t < 128) { dh[t] = 0; sh_[t] = 0; }
    __syncthreads();
#pragma unroll
    for (int i = 0; i < 16; ++i) {
        if (d_[i] >= 0) {
            int b = d_[i] >> 10;
            int p = dbase[b] + atomicAdd(&dh[b], 1);
            ebuf[p] = (unsigned)s_[i] | ((unsigned)(d_[i] & 1023) << 17);
            int bs = s_[i] >> 10;
            int q = sbase[bs] + atomicAdd(&sh_[bs], 1);
            sbuf[q] = (unsigned short)(s_[i] & 1023);
        }
    }
}

__global__ __launch_bounds__(512) void k_bucket_dst(
    const unsigned* __restrict__ ebuf, const int* __restrict__ dboff,
    const int* __restrict__ dcount, int* __restrict__ ind,
    int* __restrict__ rowp, int* __restrict__ csr, int N)
{
    __shared__ int cnt[1024];
    __shared__ int sums[512];
    int b = blockIdx.x;
    int nb0 = b << 10;
    int ncnt = min(1024, N - nb0);
    int t = threadIdx.x;
    cnt[t] = 0; cnt[t + 512] = 0;
    __syncthreads();
    int lo = dboff[b], hi = lo + dcount[b];
    for (int idx = lo + t; idx < hi; idx += 512)
        atomicAdd(&cnt[ebuf[idx] >> 17], 1);
    __syncthreads();
    int c0 = cnt[2 * t], c1 = cnt[2 * t + 1];
    sums[t] = c0 + c1;
    __syncthreads();
    for (int off = 1; off < 512; off <<= 1) {
        int x = (t >= off) ? sums[t - off] : 0;
        __syncthreads();
        sums[t] += x;
        __syncthreads();
    }
    int excl = sums[t] - (c0 + c1);
    int r0 = lo + excl, r1 = r0 + c0;
    if (2 * t < ncnt)     { rowp[nb0 + 2 * t] = r0;     ind[nb0 + 2 * t] = c0; }
    if (2 * t + 1 < ncnt) { rowp[nb0 + 2 * t + 1] = r1; ind[nb0 + 2 * t + 1] = c1; }
    __syncthreads();
    cnt[2 * t] = r0; cnt[2 * t + 1] = r1;
    __syncthreads();
    for (int idx = lo + t; idx < hi; idx += 512) {
        unsigned e = ebuf[idx];
        int p = atomicAdd(&cnt[e >> 17], 1);
        csr[p] = (int)(e & 0x1FFFF);
    }
}

__global__ __launch_bounds__(512) void k_bucket_src(
    const unsigned short* __restrict__ sbuf, const int* __restrict__ sboff,
    const int* __restrict__ scount, int* __restrict__ outd, int N)
{
    __shared__ int cnt[1024];
    int b = blockIdx.x;
    int nb0 = b << 10;
    int ncnt = min(1024, N - nb0);
    int t = threadIdx.x;
    cnt[t] = 0; cnt[t + 512] = 0;
    __syncthreads();
    int lo = sboff[b], hi = lo + scount[b];
    for (int idx = lo + t; idx < hi; idx += 512)
        atomicAdd(&cnt[sbuf[idx]], 1);
    __syncthreads();
    if (t < ncnt) outd[nb0 + t] = cnt[t];
    if (t + 512 < ncnt) outd[nb0 + t + 512] = cnt[t + 512];
}

__global__ __launch_bounds__(256) void k_norms(
    const int* __restrict__ outd, const int* __restrict__ ind, int N,
    float* __restrict__ cs, float* __restrict__ cd, int* __restrict__ didx)
{
    int i = blockIdx.x * 256 + threadIdx.x;
    if (i < N) {
        int od = outd[i], id = ind[i];
        cs[i] = rsqrtf((float)(od > 0 ? od : 1));
        cd[i] = rsqrtf((float)(id > 0 ? id : 1));
        int d = od + id;
        didx[i] = d > 511 ? 511 : d;
    }
}

// WF[k][j] = sum_m projW[k][m] * W1[64+m][j]   (512x128 fp32)
__global__ __launch_bounds__(256) void k_wf(
    const float* __restrict__ projW, const float* __restrict__ W1,
    float* __restrict__ WF)
{
    int idx = blockIdx.x * 256 + threadIdx.x;
    int k = idx >> 7, j = idx & 127;
    const float* a = projW + (size_t)k * 128;
    float s = 0.f;
#pragma unroll 8
    for (int m = 0; m < 128; ++m) s = fmaf(a[m], W1[(size_t)(64 + m) * 128 + j], s);
    WF[idx] = s;
}

__global__ void k_cb(const float* __restrict__ projb, const float* __restrict__ W1,
                     float* __restrict__ cb)
{
    int j = threadIdx.x;
    float s = 0.f;
    for (int m = 0; m < 128; ++m) s = fmaf(projb[m], W1[(size_t)(64 + m) * 128 + j], s);
    cb[j] = s;
}

// Layer-1 weights in MFMA FRAGMENT ORDER: wtf[t][ci][lane][e], t=0..19,
// ci=0..7, lane=kg*16+fr (64), e=0..7. Value = WT[col=ci*16+fr][k=t*32+kg*8+e]
// where WT col k<512: WF, k<576: W1[0:64], else W1[192:256]. idx == flat pos.
__global__ __launch_bounds__(256) void k_wt1(
    const float* __restrict__ WF, const float* __restrict__ W1,
    unsigned short* __restrict__ wtf_hi, unsigned short* __restrict__ wtf_lo)
{
    int idx = blockIdx.x * 256 + threadIdx.x;   // 20*8*64*8 = 81920
    int e = idx & 7;
    int lane = (idx >> 3) & 63;
    int ci = (idx >> 9) & 7;
    int t = idx >> 12;
    int j = ci * 16 + (lane & 15);
    int k = t * 32 + (lane >> 4) * 8 + e;
    float v;
    if (k < 512) v = WF[(size_t)k * 128 + j];
    else if (k < 576) v = W1[(size_t)(k - 512) * 128 + j];
    else v = W1[(size_t)(192 + (k - 576)) * 128 + j];
    unsigned short h = f2bf(v);
    wtf_hi[idx] = h;
    float r = v - bf2f(h);
    wtf_lo[idx] = (unsigned short)(__float_as_uint(r) >> 16);
}

// Layer-2 weights fragment order: w2tf[t][ci][lane][e], t=0..3, ci=0..3.
__global__ __launch_bounds__(256) void k_wt2(
    const float* __restrict__ W2,
    unsigned short* __restrict__ w2tf_hi, unsigned short* __restrict__ w2tf_lo)
{
    int idx = blockIdx.x * 256 + threadIdx.x;   // 4*4*64*8 = 8192
    int e = idx & 7;
    int lane = (idx >> 3) & 63;
    int ci = (idx >> 9) & 3;
    int t = idx >> 11;
    int j = ci * 16 + (lane & 15);
    int k = t * 32 + (lane >> 4) * 8 + e;
    float v = W2[(size_t)k * 64 + j];
    unsigned short h = f2bf(v);
    w2tf_hi[idx] = h;
    float r = v - bf2f(h);
    w2tf_lo[idx] = (unsigned short)(__float_as_uint(r) >> 16);
}

// ---- k_h1: A direct-from-global (dist-2 reg prefetch, slots rotate mod 2),
// B staged via global_load_lds into frag-order LDS (double-buffered 2x16KB).
// RAW s_barrier + counted vmcnt(4): loads stay in flight across barriers.
// Block = 128 rows (4 waves x 32 rows), each wave all 128 cols; K=20x32.

#define H1_STEP(t, S0, S1, S2, S3)                                            \
    {                                                                         \
        if ((t) == NT - 1) { asm volatile("s_waitcnt vmcnt(0)" ::: "memory"); } \
        else               { asm volatile("s_waitcnt vmcnt(4)" ::: "memory"); } \
        __builtin_amdgcn_sched_barrier(0);                                    \
        __builtin_amdgcn_s_barrier();                                         \
        __builtin_amdgcn_sched_barrier(0);                                    \
        const int cbuf_ = (t) & 1;                                            \
        if ((t) + 1 < NT) {                                                   \
            const unsigned short* gh_ = wtf_hi + (size_t)((t) + 1) * 4096 + tid * 8; \
            const unsigned short* gl_ = wtf_lo + (size_t)((t) + 1) * 4096 + tid * 8; \
            glds16(gh_,        &Bh[cbuf_ ^ 1][tid * 8]);                      \
            glds16(gh_ + 2048, &Bh[cbuf_ ^ 1][2048 + tid * 8]);               \
            glds16(gl_,        &Bl[cbuf_ ^ 1][tid * 8]);                      \
            glds16(gl_ + 2048, &Bl[cbuf_ ^ 1][2048 + tid * 8]);               \
        }                                                                     \
        __builtin_amdgcn_sched_barrier(0);                                    \
        short8 ah0, al0, ah1, al1;                                            \
        split_f4(S0, S1, ah0, al0);                                           \
        split_f4(S2, S3, ah1, al1);                                           \
        if ((t) + 2 < NT) {                                                   \
            const float* p0_ = aptr((t) + 2, r0, dd0);                        \
            S0 = *(const float4*)p0_;  S1 = *(const float4*)(p0_ + 4);        \
            const float* p1_ = aptr((t) + 2, r1, dd1);                        \
            S2 = *(const float4*)p1_;  S3 = *(const float4*)(p1_ + 4);        \
        }                                                                     \
        _Pragma("unroll")                                                     \
        for (int ci = 0; ci < 8; ++ci) {                                      \
            short8 bh = *(const short8*)&Bh[cbuf_][ci * 512 + lane * 8];      \
            short8 bl = *(const short8*)&Bl[cbuf_][ci * 512 + lane * 8];      \
            acc[0][ci] = __builtin_amdgcn_mfma_f32_16x16x32_bf16(ah0, bh, acc[0][ci], 0, 0, 0); \
            acc[0][ci] = __builtin_amdgcn_mfma_f32_16x16x32_bf16(al0, bh, acc[0][ci], 0, 0, 0); \
            acc[0][ci] = __builtin_amdgcn_mfma_f32_16x16x32_bf16(ah0, bl, acc[0][ci], 0, 0, 0); \
            acc[1][ci] = __builtin_amdgcn_mfma_f32_16x16x32_bf16(ah1, bh, acc[1][ci], 0, 0, 0); \
            acc[1][ci] = __builtin_amdgcn_mfma_f32_16x16x32_bf16(al1, bh, acc[1][ci], 0, 0, 0); \
            acc[1][ci] = __builtin_amdgcn_mfma_f32_16x16x32_bf16(ah1, bl, acc[1][ci], 0, 0, 0); \
        }                                                                     \
    }

__global__ __launch_bounds__(256, 2) void k_h1(
    const float* __restrict__ logits, const float* __restrict__ features,
    const float* __restrict__ deg_table, const int* __restrict__ didx,
    const unsigned short* __restrict__ wtf_hi, const unsigned short* __restrict__ wtf_lo,
    const float* __restrict__ cb, const float* __restrict__ cs,
    unsigned short* __restrict__ h1, int N)
{
    constexpr int NT = 20;
    __shared__ __align__(16) short Bh[2][4096];   // [buf][ci*512 + lane*8]
    __shared__ __align__(16) short Bl[2][4096];
    int tid = threadIdx.x;
    int lane = tid & 63, w = tid >> 6;
    int fr = lane & 15, kg = lane >> 4;
    int i0 = blockIdx.x * 128 + w * 32;
    int r0 = i0 + fr;       if (r0 >= N) r0 = N - 1;
    int r1 = i0 + 16 + fr;  if (r1 >= N) r1 = N - 1;
    int dd0 = didx[r0], dd1 = didx[r1];

    f32x4 acc[2][8];
#pragma unroll
    for (int ri = 0; ri < 2; ++ri)
#pragma unroll
        for (int ci = 0; ci < 8; ++ci) acc[ri][ci] = (f32x4)0.f;

    auto aptr = [&](int t, int r, int dd) -> const float* {
        if (t < 16) return features  + (size_t)r * 512 + t * 32 + kg * 8;
        if (t < 18) return logits    + (size_t)r * 64 + (t - 16) * 32 + kg * 8;
        return deg_table + (size_t)dd * 64 + (t - 18) * 32 + kg * 8;
    };

    // A slots (dist-2, rotate mod 2): SA = even t, SB = odd t.
    float4 SA0, SA1, SA2, SA3;
    float4 SB0, SB1, SB2, SB3;

    // prologue: B(0) glds FIRST (issue order matters for vmcnt), then A(0),A(1)
    glds16(wtf_hi + tid * 8,        &Bh[0][tid * 8]);
    glds16(wtf_hi + 2048 + tid * 8, &Bh[0][2048 + tid * 8]);
    glds16(wtf_lo + tid * 8,        &Bl[0][tid * 8]);
    glds16(wtf_lo + 2048 + tid * 8, &Bl[0][2048 + tid * 8]);
    __builtin_amdgcn_sched_barrier(0);
    {
        const float* p0_ = aptr(0, r0, dd0);
        SA0 = *(const float4*)p0_;  SA1 = *(const float4*)(p0_ + 4);
        const float* p1_ = aptr(0, r1, dd1);
        SA2 = *(const float4*)p1_;  SA3 = *(const float4*)(p1_ + 4);
        const float* q0_ = aptr(1, r0, dd0);
        SB0 = *(const float4*)q0_;  SB1 = *(const float4*)(q0_ + 4);
        const float* q1_ = aptr(1, r1, dd1);
        SB2 = *(const float4*)q1_;  SB3 = *(const float4*)(q1_ + 4);
    }

    for (int tt = 0; tt < NT; tt += 2) {
        H1_STEP(tt + 0, SA0, SA1, SA2, SA3)
        H1_STEP(tt + 1, SB0, SB1, SB2, SB3)
    }

    // C/D layout: col = ci*16 + fr, row = i0 + ri*16 + kg*4 + j  [m89]
    float cbv[8];
#pragma unroll
    for (int ci = 0; ci < 8; ++ci) cbv[ci] = cb[ci * 16 + fr];
#pragma unroll
    for (int ri = 0; ri < 2; ++ri) {
#pragma unroll
        for (int j = 0; j < 4; ++j) {
            int row = i0 + ri * 16 + kg * 4 + j;
            if (row < N) {
                float scv = cs[row];
#pragma unroll
                for (int ci = 0; ci < 8; ++ci) {
                    h1[(size_t)row * 128 + ci * 16 + fr] =
                        f2bf(scv * (acc[ri][ci][j] + cbv[ci]));
                }
            }
        }
    }
}

// Layer-1 aggregation: y[i] = relu( (sum_{e: dst=i} h1[src_e]) * cd[i] + b1 )
__global__ __launch_bounds__(256) void k_agg1(
    const unsigned short* __restrict__ h1, const int* __restrict__ rowp,
    const int* __restrict__ csr, const float* __restrict__ cd,
    const float* __restrict__ b1, float* __restrict__ y, int N)
{
    int i = blockIdx.x * 4 + (threadIdx.x >> 6);
    if (i >= N) return;
    int lane = threadIdx.x & 63;
    int s0 = rowp[i], s1 = rowp[i + 1];
    float ax = 0.f, ay = 0.f;
    int e = s0;
    for (; e + 8 <= s1; e += 8) {
        unsigned u0 = *(const unsigned*)(h1 + (size_t)csr[e + 0] * 128 + lane * 2);
        unsigned u1 = *(const unsigned*)(h1 + (size_t)csr[e + 1] * 128 + lane * 2);
        unsigned u2 = *(const unsigned*)(h1 + (size_t)csr[e + 2] * 128 + lane * 2);
        unsigned u3 = *(const unsigned*)(h1 + (size_t)csr[e + 3] * 128 + lane * 2);
        unsigned u4 = *(const unsigned*)(h1 + (size_t)csr[e + 4] * 128 + lane * 2);
        unsigned u5 = *(const unsigned*)(h1 + (size_t)csr[e + 5] * 128 + lane * 2);
        unsigned u6 = *(const unsigned*)(h1 + (size_t)csr[e + 6] * 128 + lane * 2);
        unsigned u7 = *(const unsigned*)(h1 + (size_t)csr[e + 7] * 128 + lane * 2);
        ax += ((__uint_as_float(u0 << 16) + __uint_as_float(u1 << 16)) +
               (__uint_as_float(u2 << 16) + __uint_as_float(u3 << 16))) +
              ((__uint_as_float(u4 << 16) + __uint_as_float(u5 << 16)) +
               (__uint_as_float(u6 << 16) + __uint_as_float(u7 << 16)));
        ay += ((__uint_as_float(u0 & 0xffff0000u) + __uint_as_float(u1 & 0xffff0000u)) +
               (__uint_as_float(u2 & 0xffff0000u) + __uint_as_float(u3 & 0xffff0000u))) +
              ((__uint_as_float(u4 & 0xffff0000u) + __uint_as_float(u5 & 0xffff0000u)) +
               (__uint_as_float(u6 & 0xffff0000u) + __uint_as_float(u7 & 0xffff0000u)));
    }
    for (; e < s1; ++e) {
        unsigned u = *(const unsigned*)(h1 + (size_t)csr[e] * 128 + lane * 2);
        ax += __uint_as_float(u << 16);
        ay += __uint_as_float(u & 0xffff0000u);
    }
    float cdi = cd[i];
    float2 o;
    o.x = fmaxf(fmaf(ax, cdi, b1[lane * 2 + 0]), 0.f);
    o.y = fmaxf(fmaf(ay, cdi, b1[lane * 2 + 1]), 0.f);
    *(float2*)(y + (size_t)i * 128 + lane * 2) = o;
}

// ---- k_h2: h2 = cs*(y@W2). A direct; ENTIRE fragment-order B2 (32KB)
// staged once; single barrier, then barrier-free K loop. K=4x32.
__global__ __launch_bounds__(256, 3) void k_h2(
    const float* __restrict__ y,
    const unsigned short* __restrict__ w2tf_hi, const unsigned short* __restrict__ w2tf_lo,
    const float* __restrict__ cs, unsigned short* __restrict__ h2, int N)
{
    constexpr int NT = 4;
    __shared__ __align__(16) short B2h[8192];   // [((t*4+ci)*64+lane)*8]
    __shared__ __align__(16) short B2l[8192];
    int tid = threadIdx.x;
    int lane = tid & 63, w = tid >> 6;
    int fr = lane & 15, kg = lane >> 4;
    int i0 = blockIdx.x * 128 + w * 32;
    int r0 = i0 + fr;       if (r0 >= N) r0 = N - 1;
    int r1 = i0 + 16 + fr;  if (r1 >= N) r1 = N - 1;
    const float* a0 = y + (size_t)r0 * 128 + kg * 8;
    const float* a1 = y + (size_t)r1 * 128 + kg * 8;

#pragma unroll
    for (int i = 0; i < 4; ++i) {
        *(uint4*)&B2h[(i * 256 + tid) * 8] = *(const uint4*)(w2tf_hi + (size_t)(i * 256 + tid) * 8);
        *(uint4*)&B2l[(i * 256 + tid) * 8] = *(const uint4*)(w2tf_lo + (size_t)(i * 256 + tid) * 8);
    }
    __syncthreads();

    f32x4 acc[2][4];
#pragma unroll
    for (int ri = 0; ri < 2; ++ri)
#pragma unroll
        for (int ci = 0; ci < 4; ++ci) acc[ri][ci] = (f32x4)0.f;

    float4 ar00 = *(const float4*)(a0);
    float4 ar01 = *(const float4*)(a0 + 4);
    float4 ar10 = *(const float4*)(a1);
    float4 ar11 = *(const float4*)(a1 + 4);

    for (int t = 0; t < NT; ++t) {
        short8 ah0, al0, ah1, al1;
        split_f4(ar00, ar01, ah0, al0);
        split_f4(ar10, ar11, ah1, al1);
        if (t + 1 < NT) {
            ar00 = *(const float4*)(a0 + (t + 1) * 32);
            ar01 = *(const float4*)(a0 + (t + 1) * 32 + 4);
            ar10 = *(const float4*)(a1 + (t + 1) * 32);
            ar11 = *(const float4*)(a1 + (t + 1) * 32 + 4);
        }
#pragma unroll
        for (int ci = 0; ci < 4; ++ci) {
            short8 bh = *(const short8*)&B2h[((t * 4 + ci) * 64 + lane) * 8];
            short8 bl = *(const short8*)&B2l[((t * 4 + ci) * 64 + lane) * 8];
            acc[0][ci] = __builtin_amdgcn_mfma_f32_16x16x32_bf16(ah0, bh, acc[0][ci], 0, 0, 0);
            acc[0][ci] = __builtin_amdgcn_mfma_f32_16x16x32_bf16(al0, bh, acc[0][ci], 0, 0, 0);
            acc[0][ci] = __builtin_amdgcn_mfma_f32_16x16x32_bf16(ah0, bl, acc[0][ci], 0, 0, 0);
            acc[1][ci] = __builtin_amdgcn_mfma_f32_16x16x32_bf16(ah1, bh, acc[1][ci], 0, 0, 0);
            acc[1][ci] = __builtin_amdgcn_mfma_f32_16x16x32_bf16(al1, bh, acc[1][ci], 0, 0, 0);
            acc[1][ci] = __builtin_amdgcn_mfma_f32_16x16x32_bf16(ah1, bl, acc[1][ci], 0, 0, 0);
        }
    }

#pragma unroll
    for (int ri = 0; ri < 2; ++ri) {
#pragma unroll
        for (int j = 0; j < 4; ++j) {
            int row = i0 + ri * 16 + kg * 4 + j;
            if (row < N) {
                float scv = cs[row];
#pragma unroll
                for (int ci = 0; ci < 4; ++ci) {
                    h2[(size_t)row * 64 + ci * 16 + fr] = f2bf(scv * acc[ri][ci][j]);
                }
            }
        }
    }
}

// Layer-2 aggregation: out[i] = (sum h2[src_e]) * cd[i] + b2
__global__ __launch_bounds__(256) void k_agg2(
    const unsigned short* __restrict__ h2, const int* __restrict__ rowp,
    const int* __restrict__ csr, const float* __restrict__ cd,
    const float* __restrict__ b2, float* __restrict__ out, int N)
{
    int i = blockIdx.x * 8 + (threadIdx.x >> 5);
    if (i >= N) return;
    int lane = threadIdx.x & 31;
    int s0 = rowp[i], s1 = rowp[i + 1];
    float ax = 0.f, ay = 0.f;
    int e = s0;
    for (; e + 8 <= s1; e += 8) {
        unsigned u0 = *(const unsigned*)(h2 + (size_t)csr[e + 0] * 64 + lane * 2);
        unsigned u1 = *(const unsigned*)(h2 + (size_t)csr[e + 1] * 64 + lane * 2);
        unsigned u2 = *(const unsigned*)(h2 + (size_t)csr[e + 2] * 64 + lane * 2);
        unsigned u3 = *(const unsigned*)(h2 + (size_t)csr[e + 3] * 64 + lane * 2);
        unsigned u4 = *(const unsigned*)(h2 + (size_t)csr[e + 4] * 64 + lane * 2);
        unsigned u5 = *(const unsigned*)(h2 + (size_t)csr[e + 5] * 64 + lane * 2);
        unsigned u6 = *(const unsigned*)(h2 + (size_t)csr[e + 6] * 64 + lane * 2);
        unsigned u7 = *(const unsigned*)(h2 + (size_t)csr[e + 7] * 64 + lane * 2);
        ax += ((__uint_as_float(u0 << 16) + __uint_as_float(u1 << 16)) +
               (__uint_as_float(u2 << 16) + __uint_as_float(u3 << 16))) +
              ((__uint_as_float(u4 << 16) + __uint_as_float(u5 << 16)) +
               (__uint_as_float(u6 << 16) + __uint_as_float(u7 << 16)));
        ay += ((__uint_as_float(u0 & 0xffff0000u) + __uint_as_float(u1 & 0xffff0000u)) +
               (__uint_as_float(u2 & 0xffff0000u) + __uint_as_float(u3 & 0xffff0000u))) +
              ((__uint_as_float(u4 & 0xffff0000u) + __uint_as_float(u5 & 0xffff0000u)) +
               (__uint_as_float(u6 & 0xffff0000u) + __uint_as_float(u7 & 0xffff0000u)));
    }
    for (; e < s1; ++e) {
        unsigned u = *(const unsigned*)(h2 + (size_t)csr[e] * 64 + lane * 2);
        ax += __uint_as_float(u << 16);
        ay += __uint_as_float(u & 0xffff0000u);
    }
    float cdi = cd[i];
    float2 o;
    o.x = fmaf(ax, cdi, b2[lane * 2 + 0]);
    o.y = fmaf(ay, cdi, b2[lane * 2 + 1]);
    *(float2*)(out + (size_t)i * 64 + lane * 2) = o;
}

extern "C" void kernel_launch(void* const* d_in, const int* in_sizes, int n_in,
                              void* d_out, int out_size, void* d_ws, size_t ws_size,
                              hipStream_t stream)
{
    const int* src = (const int*)d_in[0];
    const int* dst = (const int*)d_in[1];
    const float* logits = (const float*)d_in[2];
    const float* features = (const float*)d_in[3];
    const float* projW = (const float*)d_in[4];
    const float* projb = (const float*)d_in[5];
    const float* deg_table = (const float*)d_in[6];
    const float* W1 = (const float*)d_in[7];
    const float* b1 = (const float*)d_in[8];
    const float* W2 = (const float*)d_in[9];
    const float* b2 = (const float*)d_in[10];
    const int E = in_sizes[0];
    const int N = in_sizes[2] / 64;

    char* base = (char*)d_ws;
    size_t off = 0;
    auto alloc = [&](size_t bytes) -> void* {
        void* p = base + off;
        off += (bytes + 255) & ~(size_t)255;
        return p;
    };
    int* outd   = (int*)alloc((size_t)N * 4);
    int* ind    = (int*)alloc((size_t)N * 4);
    int* rowp   = (int*)alloc((size_t)(N + 1) * 4);
    int* csr    = (int*)alloc((size_t)E * 4);
    unsigned* ebuf = (unsigned*)alloc((size_t)E * 4);
    unsigned short* sbuf = (unsigned short*)alloc((size_t)E * 2);
    int* didx   = (int*)alloc((size_t)N * 4);
    float* cs   = (float*)alloc((size_t)N * 4);
    float* cd   = (float*)alloc((size_t)N * 4);
    float* WF   = (float*)alloc((size_t)512 * 128 * 4);
    float* cb   = (float*)alloc((size_t)128 * 4);
    int* dcount = (int*)alloc(128 * 4);
    int* scount = (int*)alloc(128 * 4);
    int* dboff  = (int*)alloc(128 * 4);
    int* sboff  = (int*)alloc(128 * 4);
    int* dcur   = (int*)alloc(128 * 4);
    int* scur   = (int*)alloc(128 * 4);
    unsigned short* wtf_hi  = (unsigned short*)alloc((size_t)81920 * 2);
    unsigned short* wtf_lo  = (unsigned short*)alloc((size_t)81920 * 2);
    unsigned short* w2tf_hi = (unsigned short*)alloc((size_t)8192 * 2);
    unsigned short* w2tf_lo = (unsigned short*)alloc((size_t)8192 * 2);
    unsigned short* h1 = (unsigned short*)alloc((size_t)N * 128 * 2);
    float* yb   = (float*)alloc((size_t)N * 128 * 4);
    unsigned short* h2 = h1;   // h1 dead after k_agg1; reuse
    float* outp = (float*)d_out;

    hipMemsetAsync(dcount, 0, 128 * 4, stream);
    hipMemsetAsync(scount, 0, 128 * 4, stream);

    int nb = (N + 255) / 256;
    int mb = (N + 127) / 128;
    int ebk = (E + 4095) / 4096;
    int nbuck = (N + 1023) / 1024;   // <=128 for N<=131072

    k_bcount<<<ebk, 256, 0, stream>>>(src, dst, E, dcount, scount);
    k_bscan<<<1, 128, 0, stream>>>(dcount, scount, nbuck, E, dboff, sboff, dcur, scur, rowp, N);
    k_scatter2<<<ebk, 256, 0, stream>>>(src, dst, E, dcur, scur, ebuf, sbuf, nbuck);
    k_bucket_dst<<<nbuck, 512, 0, stream>>>(ebuf, dboff, dcount, ind, rowp, csr, N);
    k_bucket_src<<<nbuck, 512, 0, stream>>>(sbuf, sboff, scount, outd, N);
    k_norms<<<nb, 256, 0, stream>>>(outd, ind, N, cs, cd, didx);
    k_wf<<<256, 256, 0, stream>>>(projW, W1, WF);
    k_cb<<<1, 128, 0, stream>>>(projb, W1, cb);
    k_wt1<<<320, 256, 0, stream>>>(WF, W1, wtf_hi, wtf_lo);
    k_wt2<<<32, 256, 0, stream>>>(W2, w2tf_hi, w2tf_lo);
    k_h1<<<mb, 256, 0, stream>>>(logits, features, deg_table, didx, wtf_hi, wtf_lo, cb, cs, h1, N);
    k_agg1<<<(N + 3) / 4, 256, 0, stream>>>(h1, rowp, csr, cd, b1, yb, N);
    k_h2<<<mb, 256, 0, stream>>>(yb, w2tf_hi, w2tf_lo, cs, h2, N);
    k_agg2<<<(N + 7) / 8, 256, 0, stream>>>(h2, rowp, csr, cd, b2, outp, N);
}

// Round 13
// 328.229 us; speedup vs baseline: 1.0171x; 1.0171x over previous
//
#include <hip/hip_runtime.h>
#include <cstdint>
#include <cstddef>

// ---------------------------------------------------------------------------
// GCN forward, MFMA edition:
//   bucketed graph preprocessing (NO scattered global atomics anywhere):
//     bcount -> bscan -> scatter2 -> bucket_dst (ind+rowp+csr) ->
//     bucket_src (outd) -> norms
//   -> WF=projW@W1mid -> WT in MFMA FRAGMENT ORDER, hi/lo bf16
//   -> h1 = cs*(x@W1+cb) [split-bf16 3-term MFMA] -> agg1 -> y=relu(...)
//   -> h2 = cs*(y@W2) -> agg2 -> out
// Split trick: a = a_hi + a_lo (bf16 trunc + bf16 residual);
// D = ahi*bhi + alo*bhi + ahi*blo -> only O(2^-17) rel. terms dropped.
// R12 lesson (4 nulls at ~118us: LDS-both / dist-1 / dist-4 / counted-vmcnt
// +glds all identical): the pin was MACRO shape, not the inner loop. Grid
// 782 = 3 blocks/CU, occupancy 25%, 8-wave barrier-locked blocks -> no TLP
// to hide per-step latency, and intra-block pipelining can't add more.
// FIX: 64-row blocks (wave = 16 rows x 128 cols, acc 32 VGPR) -> grid 1563,
// 5 blocks/CU by LDS (32KB) -> ~20 waves/CU; cross-block TLP hides the
// barrier drain (m114: waves co-schedule MFMA/VALU across blocks).
// R9 lesson: B must be LDS-shared per-block, lockstep (L1 thrash otherwise);
// frag-order B -> ds_read_b128 base+lane*16, zero bank conflicts.
// R6/R7 lesson: scattered 4B atomics across XCD L2s = ~64B writeback each;
// bucket so each 1024-node range is built by ONE block in LDS.
// R4 lesson: never cap VGPRs below acc needs (spill -> scratch traffic).
// ---------------------------------------------------------------------------

typedef short short8 __attribute__((ext_vector_type(8)));
typedef float f32x4 __attribute__((ext_vector_type(4)));

__device__ __forceinline__ unsigned short f2bf(float f) {
    unsigned u = __float_as_uint(f);
    u += 0x7fff + ((u >> 16) & 1);   // RNE
    return (unsigned short)(u >> 16);
}
__device__ __forceinline__ float bf2f(unsigned short s) {
    return __uint_as_float(((unsigned)s) << 16);
}

__device__ __forceinline__ void split_f4(float4 a, float4 b, short8& hv, short8& lv) {
    float f[8] = {a.x, a.y, a.z, a.w, b.x, b.y, b.z, b.w};
#pragma unroll
    for (int i = 0; i < 8; ++i) {
        unsigned u = __float_as_uint(f[i]);
        hv[i] = (short)(u >> 16);
        float r = f[i] - __uint_as_float(u & 0xffff0000u);
        lv[i] = (short)(__float_as_uint(r) >> 16);
    }
}

// ---- bucket preprocessing (buckets = 1024-node ranges, nb <= 128) ----

__global__ __launch_bounds__(256) void k_bcount(
    const int* __restrict__ src, const int* __restrict__ dst, int E,
    int* __restrict__ dcount, int* __restrict__ scount)
{
    __shared__ int dh[128], sh_[128];
    int t = threadIdx.x;
    if (t < 128) { dh[t] = 0; sh_[t] = 0; }
    __syncthreads();
    int e0 = blockIdx.x * 4096;
#pragma unroll
    for (int i = 0; i < 16; ++i) {
        int idx = e0 + t + i * 256;
        if (idx < E) {
            atomicAdd(&dh[dst[idx] >> 10], 1);
            atomicAdd(&sh_[src[idx] >> 10], 1);
        }
    }
    __syncthreads();
    if (t < 128) {
        if (dh[t]) atomicAdd(&dcount[t], dh[t]);
        if (sh_[t]) atomicAdd(&scount[t], sh_[t]);
    }
}

__global__ __launch_bounds__(128) void k_bscan(
    const int* __restrict__ dcount, const int* __restrict__ scount, int nb,
    int E, int* __restrict__ dboff, int* __restrict__ sboff,
    int* __restrict__ dcur, int* __restrict__ scur,
    int* __restrict__ rowp, int N)
{
    __shared__ int sh[128];
    int t = threadIdx.x;
    int v = (t < nb) ? dcount[t] : 0;
    sh[t] = v;
    __syncthreads();
    for (int off = 1; off < 128; off <<= 1) {
        int x = (t >= off) ? sh[t - off] : 0;
        __syncthreads();
        sh[t] += x;
        __syncthreads();
    }
    if (t < nb) { int e = sh[t] - v; dboff[t] = e; dcur[t] = e; }
    __syncthreads();
    int v2 = (t < nb) ? scount[t] : 0;
    sh[t] = v2;
    __syncthreads();
    for (int off = 1; off < 128; off <<= 1) {
        int x = (t >= off) ? sh[t - off] : 0;
        __syncthreads();
        sh[t] += x;
        __syncthreads();
    }
    if (t < nb) { int e = sh[t] - v2; sboff[t] = e; scur[t] = e; }
    if (t == 0) rowp[N] = E;
}

__global__ __launch_bounds__(256) void k_scatter2(
    const int* __restrict__ src, const int* __restrict__ dst, int E,
    int* __restrict__ dcur, int* __restrict__ scur,
    unsigned* __restrict__ ebuf, unsigned short* __restrict__ sbuf, int nb)
{
    __shared__ int dh[128], dbase[128], sh_[128], sbase[128];
    int t = threadIdx.x;
    int e0 = blockIdx.x * 4096;
    if (t < 128) { dh[t] = 0; sh_[t] = 0; }
    __syncthreads();
    int s_[16], d_[16];
#pragma unroll
    for (int i = 0; i < 16; ++i) {
        int idx = e0 + t + i * 256;
        if (idx < E) {
            s_[i] = src[idx];
            d_[i] = dst[idx];
            atomicAdd(&dh[d_[i] >> 10], 1);
            atomicAdd(&sh_[s_[i] >> 10], 1);
        } else d_[i] = -1;
    }
    __syncthreads();
    if (t < nb) {
        if (dh[t]) dbase[t] = atomicAdd(&dcur[t], dh[t]);
        if (sh_[t]) sbase[t] = atomicAdd(&scur[t], sh_[t]);
    }
    __syncthreads();
    if (t < 128) { dh[t] = 0; sh_[t] = 0; }
    __syncthreads();
#pragma unroll
    for (int i = 0; i < 16; ++i) {
        if (d_[i] >= 0) {
            int b = d_[i] >> 10;
            int p = dbase[b] + atomicAdd(&dh[b], 1);
            ebuf[p] = (unsigned)s_[i] | ((unsigned)(d_[i] & 1023) << 17);
            int bs = s_[i] >> 10;
            int q = sbase[bs] + atomicAdd(&sh_[bs], 1);
            sbuf[q] = (unsigned short)(s_[i] & 1023);
        }
    }
}

__global__ __launch_bounds__(512) void k_bucket_dst(
    const unsigned* __restrict__ ebuf, const int* __restrict__ dboff,
    const int* __restrict__ dcount, int* __restrict__ ind,
    int* __restrict__ rowp, int* __restrict__ csr, int N)
{
    __shared__ int cnt[1024];
    __shared__ int sums[512];
    int b = blockIdx.x;
    int nb0 = b << 10;
    int ncnt = min(1024, N - nb0);
    int t = threadIdx.x;
    cnt[t] = 0; cnt[t + 512] = 0;
    __syncthreads();
    int lo = dboff[b], hi = lo + dcount[b];
    for (int idx = lo + t; idx < hi; idx += 512)
        atomicAdd(&cnt[ebuf[idx] >> 17], 1);
    __syncthreads();
    int c0 = cnt[2 * t], c1 = cnt[2 * t + 1];
    sums[t] = c0 + c1;
    __syncthreads();
    for (int off = 1; off < 512; off <<= 1) {
        int x = (t >= off) ? sums[t - off] : 0;
        __syncthreads();
        sums[t] += x;
        __syncthreads();
    }
    int excl = sums[t] - (c0 + c1);
    int r0 = lo + excl, r1 = r0 + c0;
    if (2 * t < ncnt)     { rowp[nb0 + 2 * t] = r0;     ind[nb0 + 2 * t] = c0; }
    if (2 * t + 1 < ncnt) { rowp[nb0 + 2 * t + 1] = r1; ind[nb0 + 2 * t + 1] = c1; }
    __syncthreads();
    cnt[2 * t] = r0; cnt[2 * t + 1] = r1;
    __syncthreads();
    for (int idx = lo + t; idx < hi; idx += 512) {
        unsigned e = ebuf[idx];
        int p = atomicAdd(&cnt[e >> 17], 1);
        csr[p] = (int)(e & 0x1FFFF);
    }
}

__global__ __launch_bounds__(512) void k_bucket_src(
    const unsigned short* __restrict__ sbuf, const int* __restrict__ sboff,
    const int* __restrict__ scount, int* __restrict__ outd, int N)
{
    __shared__ int cnt[1024];
    int b = blockIdx.x;
    int nb0 = b << 10;
    int ncnt = min(1024, N - nb0);
    int t = threadIdx.x;
    cnt[t] = 0; cnt[t + 512] = 0;
    __syncthreads();
    int lo = sboff[b], hi = lo + scount[b];
    for (int idx = lo + t; idx < hi; idx += 512)
        atomicAdd(&cnt[sbuf[idx]], 1);
    __syncthreads();
    if (t < ncnt) outd[nb0 + t] = cnt[t];
    if (t + 512 < ncnt) outd[nb0 + t + 512] = cnt[t + 512];
}

__global__ __launch_bounds__(256) void k_norms(
    const int* __restrict__ outd, const int* __restrict__ ind, int N,
    float* __restrict__ cs, float* __restrict__ cd, int* __restrict__ didx)
{
    int i = blockIdx.x * 256 + threadIdx.x;
    if (i < N) {
        int od = outd[i], id = ind[i];
        cs[i] = rsqrtf((float)(od > 0 ? od : 1));
        cd[i] = rsqrtf((float)(id > 0 ? id : 1));
        int d = od + id;
        didx[i] = d > 511 ? 511 : d;
    }
}

// WF[k][j] = sum_m projW[k][m] * W1[64+m][j]   (512x128 fp32)
__global__ __launch_bounds__(256) void k_wf(
    const float* __restrict__ projW, const float* __restrict__ W1,
    float* __restrict__ WF)
{
    int idx = blockIdx.x * 256 + threadIdx.x;
    int k = idx >> 7, j = idx & 127;
    const float* a = projW + (size_t)k * 128;
    float s = 0.f;
#pragma unroll 8
    for (int m = 0; m < 128; ++m) s = fmaf(a[m], W1[(size_t)(64 + m) * 128 + j], s);
    WF[idx] = s;
}

__global__ void k_cb(const float* __restrict__ projb, const float* __restrict__ W1,
                     float* __restrict__ cb)
{
    int j = threadIdx.x;
    float s = 0.f;
    for (int m = 0; m < 128; ++m) s = fmaf(projb[m], W1[(size_t)(64 + m) * 128 + j], s);
    cb[j] = s;
}

// Layer-1 weights in MFMA FRAGMENT ORDER: wtf[t][ci][lane][e], t=0..19,
// ci=0..7, lane=kg*16+fr (64), e=0..7. Value = WT[col=ci*16+fr][k=t*32+kg*8+e]
// where WT col k<512: WF, k<576: W1[0:64], else W1[192:256]. idx == flat pos.
__global__ __launch_bounds__(256) void k_wt1(
    const float* __restrict__ WF, const float* __restrict__ W1,
    unsigned short* __restrict__ wtf_hi, unsigned short* __restrict__ wtf_lo)
{
    int idx = blockIdx.x * 256 + threadIdx.x;   // 20*8*64*8 = 81920
    int e = idx & 7;
    int lane = (idx >> 3) & 63;
    int ci = (idx >> 9) & 7;
    int t = idx >> 12;
    int j = ci * 16 + (lane & 15);
    int k = t * 32 + (lane >> 4) * 8 + e;
    float v;
    if (k < 512) v = WF[(size_t)k * 128 + j];
    else if (k < 576) v = W1[(size_t)(k - 512) * 128 + j];
    else v = W1[(size_t)(192 + (k - 576)) * 128 + j];
    unsigned short h = f2bf(v);
    wtf_hi[idx] = h;
    float r = v - bf2f(h);
    wtf_lo[idx] = (unsigned short)(__float_as_uint(r) >> 16);
}

// Layer-2 weights fragment order: w2tf[t][ci][lane][e], t=0..3, ci=0..3.
__global__ __launch_bounds__(256) void k_wt2(
    const float* __restrict__ W2,
    unsigned short* __restrict__ w2tf_hi, unsigned short* __restrict__ w2tf_lo)
{
    int idx = blockIdx.x * 256 + threadIdx.x;   // 4*4*64*8 = 8192
    int e = idx & 7;
    int lane = (idx >> 3) & 63;
    int ci = (idx >> 9) & 3;
    int t = idx >> 11;
    int j = ci * 16 + (lane & 15);
    int k = t * 32 + (lane >> 4) * 8 + e;
    float v = W2[(size_t)k * 64 + j];
    unsigned short h = f2bf(v);
    w2tf_hi[idx] = h;
    float r = v - bf2f(h);
    w2tf_lo[idx] = (unsigned short)(__float_as_uint(r) >> 16);
}

// ---- k_h1: 64-row blocks (4 waves x 16 rows, each wave all 128 cols),
// grid = N/64 = 1563 -> ~5 blocks/CU resident (LDS 32KB), ~20 waves/CU.
// A direct-from-global (frag layout == row-major; 1 row/lane, dist-1 reg
// prefetch); B staged in LDS (fragment order, double-buffered 2x16KB),
// reg-prefetch + single __syncthreads per K-step. K = 20 steps x 32.
__global__ __launch_bounds__(256, 4) void k_h1(
    const float* __restrict__ logits, const float* __restrict__ features,
    const float* __restrict__ deg_table, const int* __restrict__ didx,
    const unsigned short* __restrict__ wtf_hi, const unsigned short* __restrict__ wtf_lo,
    const float* __restrict__ cb, const float* __restrict__ cs,
    unsigned short* __restrict__ h1, int N)
{
    constexpr int NT = 20;
    __shared__ __align__(16) short Bh[2][4096];   // [buf][ci*512 + lane*8]
    __shared__ __align__(16) short Bl[2][4096];
    int tid = threadIdx.x;
    int lane = tid & 63, w = tid >> 6;
    int fr = lane & 15, kg = lane >> 4;
    int i0 = blockIdx.x * 64 + w * 16;
    int r0 = i0 + fr;  if (r0 >= N) r0 = N - 1;
    int dd0 = didx[r0];

    f32x4 acc[8];
#pragma unroll
    for (int ci = 0; ci < 8; ++ci) acc[ci] = (f32x4)0.f;

    auto aptr = [&](int t) -> const float* {
        if (t < 16) return features  + (size_t)r0 * 512 + t * 32 + kg * 8;
        if (t < 18) return logits    + (size_t)r0 * 64 + (t - 16) * 32 + kg * 8;
        return deg_table + (size_t)dd0 * 64 + (t - 18) * 32 + kg * 8;
    };

    float4 ac0, ac1;     // current A (8 floats)
    float4 an0, an1;     // next A
    uint4 sbh0, sbh1, sbl0, sbl1;

    // prologue: B(0) regs -> LDS buf0; A(0) regs
    {
        const unsigned short* g = wtf_hi + tid * 8;
        sbh0 = *(const uint4*)g;
        sbh1 = *(const uint4*)(g + 2048);
        const unsigned short* g2 = wtf_lo + tid * 8;
        sbl0 = *(const uint4*)g2;
        sbl1 = *(const uint4*)(g2 + 2048);
        *(uint4*)&Bh[0][tid * 8] = sbh0;
        *(uint4*)&Bh[0][2048 + tid * 8] = sbh1;
        *(uint4*)&Bl[0][tid * 8] = sbl0;
        *(uint4*)&Bl[0][2048 + tid * 8] = sbl1;
        const float* p = aptr(0);
        ac0 = *(const float4*)p;  ac1 = *(const float4*)(p + 4);
    }
    __syncthreads();

    for (int t = 0; t < NT; ++t) {
        int cbuf = t & 1;
        if (t + 1 < NT) {
            const unsigned short* g = wtf_hi + (size_t)(t + 1) * 4096 + tid * 8;
            sbh0 = *(const uint4*)g;
            sbh1 = *(const uint4*)(g + 2048);
            const unsigned short* g2 = wtf_lo + (size_t)(t + 1) * 4096 + tid * 8;
            sbl0 = *(const uint4*)g2;
            sbl1 = *(const uint4*)(g2 + 2048);
            const float* p = aptr(t + 1);
            an0 = *(const float4*)p;  an1 = *(const float4*)(p + 4);
        }
        short8 ah, al;
        split_f4(ac0, ac1, ah, al);
#pragma unroll
        for (int ci = 0; ci < 8; ++ci) {
            short8 bh = *(const short8*)&Bh[cbuf][ci * 512 + lane * 8];
            short8 bl = *(const short8*)&Bl[cbuf][ci * 512 + lane * 8];
            acc[ci] = __builtin_amdgcn_mfma_f32_16x16x32_bf16(ah, bh, acc[ci], 0, 0, 0);
            acc[ci] = __builtin_amdgcn_mfma_f32_16x16x32_bf16(al, bh, acc[ci], 0, 0, 0);
            acc[ci] = __builtin_amdgcn_mfma_f32_16x16x32_bf16(ah, bl, acc[ci], 0, 0, 0);
        }
        if (t + 1 < NT) {   // other buffer: its readers passed the previous barrier
            *(uint4*)&Bh[cbuf ^ 1][tid * 8] = sbh0;
            *(uint4*)&Bh[cbuf ^ 1][2048 + tid * 8] = sbh1;
            *(uint4*)&Bl[cbuf ^ 1][tid * 8] = sbl0;
            *(uint4*)&Bl[cbuf ^ 1][2048 + tid * 8] = sbl1;
            ac0 = an0;  ac1 = an1;
        }
        __syncthreads();
    }

    // C/D layout: col = ci*16 + fr, row = i0 + kg*4 + j  [m89]
    float cbv[8];
#pragma unroll
    for (int ci = 0; ci < 8; ++ci) cbv[ci] = cb[ci * 16 + fr];
#pragma unroll
    for (int j = 0; j < 4; ++j) {
        int row = i0 + kg * 4 + j;
        if (row < N) {
            float scv = cs[row];
#pragma unroll
            for (int ci = 0; ci < 8; ++ci) {
                h1[(size_t)row * 128 + ci * 16 + fr] =
                    f2bf(scv * (acc[ci][j] + cbv[ci]));
            }
        }
    }
}

// Layer-1 aggregation: y[i] = relu( (sum_{e: dst=i} h1[src_e]) * cd[i] + b1 )
__global__ __launch_bounds__(256) void k_agg1(
    const unsigned short* __restrict__ h1, const int* __restrict__ rowp,
    const int* __restrict__ csr, const float* __restrict__ cd,
    const float* __restrict__ b1, float* __restrict__ y, int N)
{
    int i = blockIdx.x * 4 + (threadIdx.x >> 6);
    if (i >= N) return;
    int lane = threadIdx.x & 63;
    int s0 = rowp[i], s1 = rowp[i + 1];
    float ax = 0.f, ay = 0.f;
    int e = s0;
    for (; e + 8 <= s1; e += 8) {
        unsigned u0 = *(const unsigned*)(h1 + (size_t)csr[e + 0] * 128 + lane * 2);
        unsigned u1 = *(const unsigned*)(h1 + (size_t)csr[e + 1] * 128 + lane * 2);
        unsigned u2 = *(const unsigned*)(h1 + (size_t)csr[e + 2] * 128 + lane * 2);
        unsigned u3 = *(const unsigned*)(h1 + (size_t)csr[e + 3] * 128 + lane * 2);
        unsigned u4 = *(const unsigned*)(h1 + (size_t)csr[e + 4] * 128 + lane * 2);
        unsigned u5 = *(const unsigned*)(h1 + (size_t)csr[e + 5] * 128 + lane * 2);
        unsigned u6 = *(const unsigned*)(h1 + (size_t)csr[e + 6] * 128 + lane * 2);
        unsigned u7 = *(const unsigned*)(h1 + (size_t)csr[e + 7] * 128 + lane * 2);
        ax += ((__uint_as_float(u0 << 16) + __uint_as_float(u1 << 16)) +
               (__uint_as_float(u2 << 16) + __uint_as_float(u3 << 16))) +
              ((__uint_as_float(u4 << 16) + __uint_as_float(u5 << 16)) +
               (__uint_as_float(u6 << 16) + __uint_as_float(u7 << 16)));
        ay += ((__uint_as_float(u0 & 0xffff0000u) + __uint_as_float(u1 & 0xffff0000u)) +
               (__uint_as_float(u2 & 0xffff0000u) + __uint_as_float(u3 & 0xffff0000u))) +
              ((__uint_as_float(u4 & 0xffff0000u) + __uint_as_float(u5 & 0xffff0000u)) +
               (__uint_as_float(u6 & 0xffff0000u) + __uint_as_float(u7 & 0xffff0000u)));
    }
    for (; e < s1; ++e) {
        unsigned u = *(const unsigned*)(h1 + (size_t)csr[e] * 128 + lane * 2);
        ax += __uint_as_float(u << 16);
        ay += __uint_as_float(u & 0xffff0000u);
    }
    float cdi = cd[i];
    float2 o;
    o.x = fmaxf(fmaf(ax, cdi, b1[lane * 2 + 0]), 0.f);
    o.y = fmaxf(fmaf(ay, cdi, b1[lane * 2 + 1]), 0.f);
    *(float2*)(y + (size_t)i * 128 + lane * 2) = o;
}

// ---- k_h2: h2 = cs*(y@W2). A direct; ENTIRE fragment-order B2 (32KB)
// staged once; single barrier, then barrier-free K loop. K=4x32.
__global__ __launch_bounds__(256, 3) void k_h2(
    const float* __restrict__ y,
    const unsigned short* __restrict__ w2tf_hi, const unsigned short* __restrict__ w2tf_lo,
    const float* __restrict__ cs, unsigned short* __restrict__ h2, int N)
{
    constexpr int NT = 4;
    __shared__ __align__(16) short B2h[8192];   // [((t*4+ci)*64+lane)*8]
    __shared__ __align__(16) short B2l[8192];
    int tid = threadIdx.x;
    int lane = tid & 63, w = tid >> 6;
    int fr = lane & 15, kg = lane >> 4;
    int i0 = blockIdx.x * 128 + w * 32;
    int r0 = i0 + fr;       if (r0 >= N) r0 = N - 1;
    int r1 = i0 + 16 + fr;  if (r1 >= N) r1 = N - 1;
    const float* a0 = y + (size_t)r0 * 128 + kg * 8;
    const float* a1 = y + (size_t)r1 * 128 + kg * 8;

#pragma unroll
    for (int i = 0; i < 4; ++i) {
        *(uint4*)&B2h[(i * 256 + tid) * 8] = *(const uint4*)(w2tf_hi + (size_t)(i * 256 + tid) * 8);
        *(uint4*)&B2l[(i * 256 + tid) * 8] = *(const uint4*)(w2tf_lo + (size_t)(i * 256 + tid) * 8);
    }
    __syncthreads();

    f32x4 acc[2][4];
#pragma unroll
    for (int ri = 0; ri < 2; ++ri)
#pragma unroll
        for (int ci = 0; ci < 4; ++ci) acc[ri][ci] = (f32x4)0.f;

    float4 ar00 = *(const float4*)(a0);
    float4 ar01 = *(const float4*)(a0 + 4);
    float4 ar10 = *(const float4*)(a1);
    float4 ar11 = *(const float4*)(a1 + 4);

    for (int t = 0; t < NT; ++t) {
        short8 ah0, al0, ah1, al1;
        split_f4(ar00, ar01, ah0, al0);
        split_f4(ar10, ar11, ah1, al1);
        if (t + 1 < NT) {
            ar00 = *(const float4*)(a0 + (t + 1) * 32);
            ar01 = *(const float4*)(a0 + (t + 1) * 32 + 4);
            ar10 = *(const float4*)(a1 + (t + 1) * 32);
            ar11 = *(const float4*)(a1 + (t + 1) * 32 + 4);
        }
#pragma unroll
        for (int ci = 0; ci < 4; ++ci) {
            short8 bh = *(const short8*)&B2h[((t * 4 + ci) * 64 + lane) * 8];
            short8 bl = *(const short8*)&B2l[((t * 4 + ci) * 64 + lane) * 8];
            acc[0][ci] = __builtin_amdgcn_mfma_f32_16x16x32_bf16(ah0, bh, acc[0][ci], 0, 0, 0);
            acc[0][ci] = __builtin_amdgcn_mfma_f32_16x16x32_bf16(al0, bh, acc[0][ci], 0, 0, 0);
            acc[0][ci] = __builtin_amdgcn_mfma_f32_16x16x32_bf16(ah0, bl, acc[0][ci], 0, 0, 0);
            acc[1][ci] = __builtin_amdgcn_mfma_f32_16x16x32_bf16(ah1, bh, acc[1][ci], 0, 0, 0);
            acc[1][ci] = __builtin_amdgcn_mfma_f32_16x16x32_bf16(al1, bh, acc[1][ci], 0, 0, 0);
            acc[1][ci] = __builtin_amdgcn_mfma_f32_16x16x32_bf16(ah1, bl, acc[1][ci], 0, 0, 0);
        }
    }

#pragma unroll
    for (int ri = 0; ri < 2; ++ri) {
#pragma unroll
        for (int j = 0; j < 4; ++j) {
            int row = i0 + ri * 16 + kg * 4 + j;
            if (row < N) {
                float scv = cs[row];
#pragma unroll
                for (int ci = 0; ci < 4; ++ci) {
                    h2[(size_t)row * 64 + ci * 16 + fr] = f2bf(scv * acc[ri][ci][j]);
                }
            }
        }
    }
}

// Layer-2 aggregation: out[i] = (sum h2[src_e]) * cd[i] + b2
__global__ __launch_bounds__(256) void k_agg2(
    const unsigned short* __restrict__ h2, const int* __restrict__ rowp,
    const int* __restrict__ csr, const float* __restrict__ cd,
    const float* __restrict__ b2, float* __restrict__ out, int N)
{
    int i = blockIdx.x * 8 + (threadIdx.x >> 5);
    if (i >= N) return;
    int lane = threadIdx.x & 31;
    int s0 = rowp[i], s1 = rowp[i + 1];
    float ax = 0.f, ay = 0.f;
    int e = s0;
    for (; e + 8 <= s1; e += 8) {
        unsigned u0 = *(const unsigned*)(h2 + (size_t)csr[e + 0] * 64 + lane * 2);
        unsigned u1 = *(const unsigned*)(h2 + (size_t)csr[e + 1] * 64 + lane * 2);
        unsigned u2 = *(const unsigned*)(h2 + (size_t)csr[e + 2] * 64 + lane * 2);
        unsigned u3 = *(const unsigned*)(h2 + (size_t)csr[e + 3] * 64 + lane * 2);
        unsigned u4 = *(const unsigned*)(h2 + (size_t)csr[e + 4] * 64 + lane * 2);
        unsigned u5 = *(const unsigned*)(h2 + (size_t)csr[e + 5] * 64 + lane * 2);
        unsigned u6 = *(const unsigned*)(h2 + (size_t)csr[e + 6] * 64 + lane * 2);
        unsigned u7 = *(const unsigned*)(h2 + (size_t)csr[e + 7] * 64 + lane * 2);
        ax += ((__uint_as_float(u0 << 16) + __uint_as_float(u1 << 16)) +
               (__uint_as_float(u2 << 16) + __uint_as_float(u3 << 16))) +
              ((__uint_as_float(u4 << 16) + __uint_as_float(u5 << 16)) +
               (__uint_as_float(u6 << 16) + __uint_as_float(u7 << 16)));
        ay += ((__uint_as_float(u0 & 0xffff0000u) + __uint_as_float(u1 & 0xffff0000u)) +
               (__uint_as_float(u2 & 0xffff0000u) + __uint_as_float(u3 & 0xffff0000u))) +
              ((__uint_as_float(u4 & 0xffff0000u) + __uint_as_float(u5 & 0xffff0000u)) +
               (__uint_as_float(u6 & 0xffff0000u) + __uint_as_float(u7 & 0xffff0000u)));
    }
    for (; e < s1; ++e) {
        unsigned u = *(const unsigned*)(h2 + (size_t)csr[e] * 64 + lane * 2);
        ax += __uint_as_float(u << 16);
        ay += __uint_as_float(u & 0xffff0000u);
    }
    float cdi = cd[i];
    float2 o;
    o.x = fmaf(ax, cdi, b2[lane * 2 + 0]);
    o.y = fmaf(ay, cdi, b2[lane * 2 + 1]);
    *(float2*)(out + (size_t)i * 64 + lane * 2) = o;
}

extern "C" void kernel_launch(void* const* d_in, const int* in_sizes, int n_in,
                              void* d_out, int out_size, void* d_ws, size_t ws_size,
                              hipStream_t stream)
{
    const int* src = (const int*)d_in[0];
    const int* dst = (const int*)d_in[1];
    const float* logits = (const float*)d_in[2];
    const float* features = (const float*)d_in[3];
    const float* projW = (const float*)d_in[4];
    const float* projb = (const float*)d_in[5];
    const float* deg_table = (const float*)d_in[6];
    const float* W1 = (const float*)d_in[7];
    const float* b1 = (const float*)d_in[8];
    const float* W2 = (const float*)d_in[9];
    const float* b2 = (const float*)d_in[10];
    const int E = in_sizes[0];
    const int N = in_sizes[2] / 64;

    char* base = (char*)d_ws;
    size_t off = 0;
    auto alloc = [&](size_t bytes) -> void* {
        void* p = base + off;
        off += (bytes + 255) & ~(size_t)255;
        return p;
    };
    int* outd   = (int*)alloc((size_t)N * 4);
    int* ind    = (int*)alloc((size_t)N * 4);
    int* rowp   = (int*)alloc((size_t)(N + 1) * 4);
    int* csr    = (int*)alloc((size_t)E * 4);
    unsigned* ebuf = (unsigned*)alloc((size_t)E * 4);
    unsigned short* sbuf = (unsigned short*)alloc((size_t)E * 2);
    int* didx   = (int*)alloc((size_t)N * 4);
    float* cs   = (float*)alloc((size_t)N * 4);
    float* cd   = (float*)alloc((size_t)N * 4);
    float* WF   = (float*)alloc((size_t)512 * 128 * 4);
    float* cb   = (float*)alloc((size_t)128 * 4);
    int* dcount = (int*)alloc(128 * 4);
    int* scount = (int*)alloc(128 * 4);
    int* dboff  = (int*)alloc(128 * 4);
    int* sboff  = (int*)alloc(128 * 4);
    int* dcur   = (int*)alloc(128 * 4);
    int* scur   = (int*)alloc(128 * 4);
    unsigned short* wtf_hi  = (unsigned short*)alloc((size_t)81920 * 2);
    unsigned short* wtf_lo  = (unsigned short*)alloc((size_t)81920 * 2);
    unsigned short* w2tf_hi = (unsigned short*)alloc((size_t)8192 * 2);
    unsigned short* w2tf_lo = (unsigned short*)alloc((size_t)8192 * 2);
    unsigned short* h1 = (unsigned short*)alloc((size_t)N * 128 * 2);
    float* yb   = (float*)alloc((size_t)N * 128 * 4);
    unsigned short* h2 = h1;   // h1 dead after k_agg1; reuse
    float* outp = (float*)d_out;

    hipMemsetAsync(dcount, 0, 128 * 4, stream);
    hipMemsetAsync(scount, 0, 128 * 4, stream);

    int nb = (N + 255) / 256;
    int mb1 = (N + 63) / 64;     // 64-row k_h1 blocks
    int mb2 = (N + 127) / 128;   // 128-row k_h2 blocks
    int ebk = (E + 4095) / 4096;
    int nbuck = (N + 1023) / 1024;   // <=128 for N<=131072

    k_bcount<<<ebk, 256, 0, stream>>>(src, dst, E, dcount, scount);
    k_bscan<<<1, 128, 0, stream>>>(dcount, scount, nbuck, E, dboff, sboff, dcur, scur, rowp, N);
    k_scatter2<<<ebk, 256, 0, stream>>>(src, dst, E, dcur, scur, ebuf, sbuf, nbuck);
    k_bucket_dst<<<nbuck, 512, 0, stream>>>(ebuf, dboff, dcount, ind, rowp, csr, N);
    k_bucket_src<<<nbuck, 512, 0, stream>>>(sbuf, sboff, scount, outd, N);
    k_norms<<<nb, 256, 0, stream>>>(outd, ind, N, cs, cd, didx);
    k_wf<<<256, 256, 0, stream>>>(projW, W1, WF);
    k_cb<<<1, 128, 0, stream>>>(projb, W1, cb);
    k_wt1<<<320, 256, 0, stream>>>(WF, W1, wtf_hi, wtf_lo);
    k_wt2<<<32, 256, 0, stream>>>(W2, w2tf_hi, w2tf_lo);
    k_h1<<<mb1, 256, 0, stream>>>(logits, features, deg_table, didx, wtf_hi, wtf_lo, cb, cs, h1, N);
    k_agg1<<<(N + 3) / 4, 256, 0, stream>>>(h1, rowp, csr, cd, b1, yb, N);
    k_h2<<<mb2, 256, 0, stream>>>(yb, w2tf_hi, w2tf_lo, cs, h2, N);
    k_agg2<<<(N + 7) / 8, 256, 0, stream>>>(h2, rowp, csr, cd, b2, outp, N);
}

// Round 14
// 309.444 us; speedup vs baseline: 1.0789x; 1.0607x over previous
//
#include <hip/hip_runtime.h>
#include <cstdint>
#include <cstddef>

// ---------------------------------------------------------------------------
// GCN forward, MFMA edition:
//   bucketed graph preprocessing (NO scattered global atomics anywhere):
//     bcount -> bscan -> scatter2 -> bucket_dst (ind+rowp+csr) ->
//     bucket_src (outd in LDS + cs/cd/didx fused) 
//   -> WF=projW@W1mid (+cb fused) -> WT frag-order hi/lo bf16 (wt1+wt2 fused)
//   -> h1 = cs*(x@W1+cb) [split-bf16 3-term MFMA] -> agg1 -> y=relu(...)
//   -> h2 = cs*(y@W2) -> agg2 -> out
// Split trick: a = a_hi + a_lo (bf16 trunc + bf16 residual);
// D = ahi*bhi + alo*bhi + ahi*blo -> only O(2^-17) rel. terms dropped.
// R13 lesson: 6 structural k_h1 variants all ~110-120us with FETCH/dur
// ~1.0-1.2 TB/s constant -> pin is the A-access DRAM pattern (64x128B
// strided chunks/step), not scheduling. k_h1 frozen this round; pivot to
// aggs + launch-count. agg1 now 32-lane/node uint2 gathers (2x wave-level
// node parallelism, same bytes) like agg2.
// R9 lesson: B must be LDS-shared per-block, lockstep (frag-order ->
// ds_read_b128 base+lane*16, zero bank conflicts).
// R6/R7 lesson: scattered 4B atomics across XCD L2s = ~64B writeback each;
// bucket so each 1024-node range is built by ONE block in LDS.
// R4 lesson: never cap VGPRs below acc needs (spill -> scratch traffic).
// ---------------------------------------------------------------------------

typedef short short8 __attribute__((ext_vector_type(8)));
typedef float f32x4 __attribute__((ext_vector_type(4)));

__device__ __forceinline__ unsigned short f2bf(float f) {
    unsigned u = __float_as_uint(f);
    u += 0x7fff + ((u >> 16) & 1);   // RNE
    return (unsigned short)(u >> 16);
}
__device__ __forceinline__ float bf2f(unsigned short s) {
    return __uint_as_float(((unsigned)s) << 16);
}

__device__ __forceinline__ void split_f4(float4 a, float4 b, short8& hv, short8& lv) {
    float f[8] = {a.x, a.y, a.z, a.w, b.x, b.y, b.z, b.w};
#pragma unroll
    for (int i = 0; i < 8; ++i) {
        unsigned u = __float_as_uint(f[i]);
        hv[i] = (short)(u >> 16);
        float r = f[i] - __uint_as_float(u & 0xffff0000u);
        lv[i] = (short)(__float_as_uint(r) >> 16);
    }
}

// ---- bucket preprocessing (buckets = 1024-node ranges, nb <= 128) ----

__global__ __launch_bounds__(256) void k_bcount(
    const int* __restrict__ src, const int* __restrict__ dst, int E,
    int* __restrict__ dcount, int* __restrict__ scount)
{
    __shared__ int dh[128], sh_[128];
    int t = threadIdx.x;
    if (t < 128) { dh[t] = 0; sh_[t] = 0; }
    __syncthreads();
    int e0 = blockIdx.x * 4096;
#pragma unroll
    for (int i = 0; i < 16; ++i) {
        int idx = e0 + t + i * 256;
        if (idx < E) {
            atomicAdd(&dh[dst[idx] >> 10], 1);
            atomicAdd(&sh_[src[idx] >> 10], 1);
        }
    }
    __syncthreads();
    if (t < 128) {
        if (dh[t]) atomicAdd(&dcount[t], dh[t]);
        if (sh_[t]) atomicAdd(&scount[t], sh_[t]);
    }
}

__global__ __launch_bounds__(128) void k_bscan(
    const int* __restrict__ dcount, const int* __restrict__ scount, int nb,
    int E, int* __restrict__ dboff, int* __restrict__ sboff,
    int* __restrict__ dcur, int* __restrict__ scur,
    int* __restrict__ rowp, int N)
{
    __shared__ int sh[128];
    int t = threadIdx.x;
    int v = (t < nb) ? dcount[t] : 0;
    sh[t] = v;
    __syncthreads();
    for (int off = 1; off < 128; off <<= 1) {
        int x = (t >= off) ? sh[t - off] : 0;
        __syncthreads();
        sh[t] += x;
        __syncthreads();
    }
    if (t < nb) { int e = sh[t] - v; dboff[t] = e; dcur[t] = e; }
    __syncthreads();
    int v2 = (t < nb) ? scount[t] : 0;
    sh[t] = v2;
    __syncthreads();
    for (int off = 1; off < 128; off <<= 1) {
        int x = (t >= off) ? sh[t - off] : 0;
        __syncthreads();
        sh[t] += x;
        __syncthreads();
    }
    if (t < nb) { int e = sh[t] - v2; sboff[t] = e; scur[t] = e; }
    if (t == 0) rowp[N] = E;
}

__global__ __launch_bounds__(256) void k_scatter2(
    const int* __restrict__ src, const int* __restrict__ dst, int E,
    int* __restrict__ dcur, int* __restrict__ scur,
    unsigned* __restrict__ ebuf, unsigned short* __restrict__ sbuf, int nb)
{
    __shared__ int dh[128], dbase[128], sh_[128], sbase[128];
    int t = threadIdx.x;
    int e0 = blockIdx.x * 4096;
    if (t < 128) { dh[t] = 0; sh_[t] = 0; }
    __syncthreads();
    int s_[16], d_[16];
#pragma unroll
    for (int i = 0; i < 16; ++i) {
        int idx = e0 + t + i * 256;
        if (idx < E) {
            s_[i] = src[idx];
            d_[i] = dst[idx];
            atomicAdd(&dh[d_[i] >> 10], 1);
            atomicAdd(&sh_[s_[i] >> 10], 1);
        } else d_[i] = -1;
    }
    __syncthreads();
    if (t < nb) {
        if (dh[t]) dbase[t] = atomicAdd(&dcur[t], dh[t]);
        if (sh_[t]) sbase[t] = atomicAdd(&scur[t], sh_[t]);
    }
    __syncthreads();
    if (t < 128) { dh[t] = 0; sh_[t] = 0; }
    __syncthreads();
#pragma unroll
    for (int i = 0; i < 16; ++i) {
        if (d_[i] >= 0) {
            int b = d_[i] >> 10;
            int p = dbase[b] + atomicAdd(&dh[b], 1);
            ebuf[p] = (unsigned)s_[i] | ((unsigned)(d_[i] & 1023) << 17);
            int bs = s_[i] >> 10;
            int q = sbase[bs] + atomicAdd(&sh_[bs], 1);
            sbuf[q] = (unsigned short)(s_[i] & 1023);
        }
    }
}

__global__ __launch_bounds__(512) void k_bucket_dst(
    const unsigned* __restrict__ ebuf, const int* __restrict__ dboff,
    const int* __restrict__ dcount, int* __restrict__ ind,
    int* __restrict__ rowp, int* __restrict__ csr, int N)
{
    __shared__ int cnt[1024];
    __shared__ int sums[512];
    int b = blockIdx.x;
    int nb0 = b << 10;
    int ncnt = min(1024, N - nb0);
    int t = threadIdx.x;
    cnt[t] = 0; cnt[t + 512] = 0;
    __syncthreads();
    int lo = dboff[b], hi = lo + dcount[b];
    for (int idx = lo + t; idx < hi; idx += 512)
        atomicAdd(&cnt[ebuf[idx] >> 17], 1);
    __syncthreads();
    int c0 = cnt[2 * t], c1 = cnt[2 * t + 1];
    sums[t] = c0 + c1;
    __syncthreads();
    for (int off = 1; off < 512; off <<= 1) {
        int x = (t >= off) ? sums[t - off] : 0;
        __syncthreads();
        sums[t] += x;
        __syncthreads();
    }
    int excl = sums[t] - (c0 + c1);
    int r0 = lo + excl, r1 = r0 + c0;
    if (2 * t < ncnt)     { rowp[nb0 + 2 * t] = r0;     ind[nb0 + 2 * t] = c0; }
    if (2 * t + 1 < ncnt) { rowp[nb0 + 2 * t + 1] = r1; ind[nb0 + 2 * t + 1] = c1; }
    __syncthreads();
    cnt[2 * t] = r0; cnt[2 * t + 1] = r1;
    __syncthreads();
    for (int idx = lo + t; idx < hi; idx += 512) {
        unsigned e = ebuf[idx];
        int p = atomicAdd(&cnt[e >> 17], 1);
        csr[p] = (int)(e & 0x1FFFF);
    }
}

// one block per bucket: out-degree histogram in LDS, then cs/cd/didx fused
// (norms kernel eliminated; outd never hits global memory).
__global__ __launch_bounds__(512) void k_bucket_src(
    const unsigned short* __restrict__ sbuf, const int* __restrict__ sboff,
    const int* __restrict__ scount, const int* __restrict__ ind,
    float* __restrict__ cs, float* __restrict__ cd, int* __restrict__ didx,
    int N)
{
    __shared__ int cnt[1024];
    int b = blockIdx.x;
    int nb0 = b << 10;
    int ncnt = min(1024, N - nb0);
    int t = threadIdx.x;
    cnt[t] = 0; cnt[t + 512] = 0;
    __syncthreads();
    int lo = sboff[b], hi = lo + scount[b];
    for (int idx = lo + t; idx < hi; idx += 512)
        atomicAdd(&cnt[sbuf[idx]], 1);
    __syncthreads();
#pragma unroll
    for (int k = 0; k < 2; ++k) {
        int loc = t + k * 512;
        if (loc < ncnt) {
            int od = cnt[loc];
            int id = ind[nb0 + loc];
            cs[nb0 + loc] = rsqrtf((float)(od > 0 ? od : 1));
            cd[nb0 + loc] = rsqrtf((float)(id > 0 ? id : 1));
            int d = od + id;
            didx[nb0 + loc] = d > 511 ? 511 : d;
        }
    }
}

// WF[k][j] = sum_m projW[k][m] * W1[64+m][j] (512x128 fp32); block 256 = cb
__global__ __launch_bounds__(256) void k_wf(
    const float* __restrict__ projW, const float* __restrict__ projb,
    const float* __restrict__ W1, float* __restrict__ WF,
    float* __restrict__ cb)
{
    if (blockIdx.x == 256) {
        int j = threadIdx.x;
        if (j < 128) {
            float s = 0.f;
            for (int m = 0; m < 128; ++m)
                s = fmaf(projb[m], W1[(size_t)(64 + m) * 128 + j], s);
            cb[j] = s;
        }
        return;
    }
    int idx = blockIdx.x * 256 + threadIdx.x;
    int k = idx >> 7, j = idx & 127;
    const float* a = projW + (size_t)k * 128;
    float s = 0.f;
#pragma unroll 8
    for (int m = 0; m < 128; ++m) s = fmaf(a[m], W1[(size_t)(64 + m) * 128 + j], s);
    WF[idx] = s;
}

// Fused weight-fragment kernel: idx<81920 -> layer1 wtf; else layer2 w2tf.
// Layer-1: wtf[t][ci][lane][e], t=0..19, ci=0..7, lane=kg*16+fr, e=0..7;
// value = WT[col=ci*16+fr][k=t*32+kg*8+e], col source WF/W1[0:64]/W1[192:256].
// Layer-2: w2tf[t][ci][lane][e], t=0..3, ci=0..3, from W2 (128x64).
__global__ __launch_bounds__(256) void k_wt(
    const float* __restrict__ WF, const float* __restrict__ W1,
    const float* __restrict__ W2,
    unsigned short* __restrict__ wtf_hi, unsigned short* __restrict__ wtf_lo,
    unsigned short* __restrict__ w2tf_hi, unsigned short* __restrict__ w2tf_lo)
{
    int idx = blockIdx.x * 256 + threadIdx.x;   // 81920 + 8192 = 90112
    if (idx < 81920) {
        int e = idx & 7;
        int lane = (idx >> 3) & 63;
        int ci = (idx >> 9) & 7;
        int t = idx >> 12;
        int j = ci * 16 + (lane & 15);
        int k = t * 32 + (lane >> 4) * 8 + e;
        float v;
        if (k < 512) v = WF[(size_t)k * 128 + j];
        else if (k < 576) v = W1[(size_t)(k - 512) * 128 + j];
        else v = W1[(size_t)(192 + (k - 576)) * 128 + j];
        unsigned short h = f2bf(v);
        wtf_hi[idx] = h;
        float r = v - bf2f(h);
        wtf_lo[idx] = (unsigned short)(__float_as_uint(r) >> 16);
    } else if (idx < 90112) {
        int i2 = idx - 81920;
        int e = i2 & 7;
        int lane = (i2 >> 3) & 63;
        int ci = (i2 >> 9) & 3;
        int t = i2 >> 11;
        int j = ci * 16 + (lane & 15);
        int k = t * 32 + (lane >> 4) * 8 + e;
        float v = W2[(size_t)k * 64 + j];
        unsigned short h = f2bf(v);
        w2tf_hi[i2] = h;
        float r = v - bf2f(h);
        w2tf_lo[i2] = (unsigned short)(__float_as_uint(r) >> 16);
    }
}

// ---- k_h1 (UNCHANGED from R13): 64-row blocks (4 waves x 16 rows), A
// direct-from-global dist-1 reg prefetch, B frag-order LDS double-buffer.
__global__ __launch_bounds__(256, 4) void k_h1(
    const float* __restrict__ logits, const float* __restrict__ features,
    const float* __restrict__ deg_table, const int* __restrict__ didx,
    const unsigned short* __restrict__ wtf_hi, const unsigned short* __restrict__ wtf_lo,
    const float* __restrict__ cb, const float* __restrict__ cs,
    unsigned short* __restrict__ h1, int N)
{
    constexpr int NT = 20;
    __shared__ __align__(16) short Bh[2][4096];
    __shared__ __align__(16) short Bl[2][4096];
    int tid = threadIdx.x;
    int lane = tid & 63, w = tid >> 6;
    int fr = lane & 15, kg = lane >> 4;
    int i0 = blockIdx.x * 64 + w * 16;
    int r0 = i0 + fr;  if (r0 >= N) r0 = N - 1;
    int dd0 = didx[r0];

    f32x4 acc[8];
#pragma unroll
    for (int ci = 0; ci < 8; ++ci) acc[ci] = (f32x4)0.f;

    auto aptr = [&](int t) -> const float* {
        if (t < 16) return features  + (size_t)r0 * 512 + t * 32 + kg * 8;
        if (t < 18) return logits    + (size_t)r0 * 64 + (t - 16) * 32 + kg * 8;
        return deg_table + (size_t)dd0 * 64 + (t - 18) * 32 + kg * 8;
    };

    float4 ac0, ac1, an0, an1;
    uint4 sbh0, sbh1, sbl0, sbl1;

    {
        const unsigned short* g = wtf_hi + tid * 8;
        sbh0 = *(const uint4*)g;
        sbh1 = *(const uint4*)(g + 2048);
        const unsigned short* g2 = wtf_lo + tid * 8;
        sbl0 = *(const uint4*)g2;
        sbl1 = *(const uint4*)(g2 + 2048);
        *(uint4*)&Bh[0][tid * 8] = sbh0;
        *(uint4*)&Bh[0][2048 + tid * 8] = sbh1;
        *(uint4*)&Bl[0][tid * 8] = sbl0;
        *(uint4*)&Bl[0][2048 + tid * 8] = sbl1;
        const float* p = aptr(0);
        ac0 = *(const float4*)p;  ac1 = *(const float4*)(p + 4);
    }
    __syncthreads();

    for (int t = 0; t < NT; ++t) {
        int cbuf = t & 1;
        if (t + 1 < NT) {
            const unsigned short* g = wtf_hi + (size_t)(t + 1) * 4096 + tid * 8;
            sbh0 = *(const uint4*)g;
            sbh1 = *(const uint4*)(g + 2048);
            const unsigned short* g2 = wtf_lo + (size_t)(t + 1) * 4096 + tid * 8;
            sbl0 = *(const uint4*)g2;
            sbl1 = *(const uint4*)(g2 + 2048);
            const float* p = aptr(t + 1);
            an0 = *(const float4*)p;  an1 = *(const float4*)(p + 4);
        }
        short8 ah, al;
        split_f4(ac0, ac1, ah, al);
#pragma unroll
        for (int ci = 0; ci < 8; ++ci) {
            short8 bh = *(const short8*)&Bh[cbuf][ci * 512 + lane * 8];
            short8 bl = *(const short8*)&Bl[cbuf][ci * 512 + lane * 8];
            acc[ci] = __builtin_amdgcn_mfma_f32_16x16x32_bf16(ah, bh, acc[ci], 0, 0, 0);
            acc[ci] = __builtin_amdgcn_mfma_f32_16x16x32_bf16(al, bh, acc[ci], 0, 0, 0);
            acc[ci] = __builtin_amdgcn_mfma_f32_16x16x32_bf16(ah, bl, acc[ci], 0, 0, 0);
        }
        if (t + 1 < NT) {
            *(uint4*)&Bh[cbuf ^ 1][tid * 8] = sbh0;
            *(uint4*)&Bh[cbuf ^ 1][2048 + tid * 8] = sbh1;
            *(uint4*)&Bl[cbuf ^ 1][tid * 8] = sbl0;
            *(uint4*)&Bl[cbuf ^ 1][2048 + tid * 8] = sbl1;
            ac0 = an0;  ac1 = an1;
        }
        __syncthreads();
    }

    float cbv[8];
#pragma unroll
    for (int ci = 0; ci < 8; ++ci) cbv[ci] = cb[ci * 16 + fr];
#pragma unroll
    for (int j = 0; j < 4; ++j) {
        int row = i0 + kg * 4 + j;
        if (row < N) {
            float scv = cs[row];
#pragma unroll
            for (int ci = 0; ci < 8; ++ci) {
                h1[(size_t)row * 128 + ci * 16 + fr] =
                    f2bf(scv * (acc[ci][j] + cbv[ci]));
            }
        }
    }
}

// Layer-1 aggregation: y[i] = relu( (sum_{e: dst=i} h1[src_e]) * cd[i] + b1 )
// 32-lane half-wave per node (uint2 = 4 bf16 cols per lane), unroll 8:
// 2x node-parallelism per wave vs the old 64-lane/node form.
__global__ __launch_bounds__(256) void k_agg1(
    const unsigned short* __restrict__ h1, const int* __restrict__ rowp,
    const int* __restrict__ csr, const float* __restrict__ cd,
    const float* __restrict__ b1, float* __restrict__ y, int N)
{
    int i = blockIdx.x * 8 + (threadIdx.x >> 5);
    if (i >= N) return;
    int lane = threadIdx.x & 31;
    int s0 = rowp[i], s1 = rowp[i + 1];
    float a0 = 0.f, a1 = 0.f, a2 = 0.f, a3 = 0.f;
    int e = s0;
    for (; e + 8 <= s1; e += 8) {
        uint2 v0 = *(const uint2*)(h1 + (size_t)csr[e + 0] * 128 + lane * 4);
        uint2 v1 = *(const uint2*)(h1 + (size_t)csr[e + 1] * 128 + lane * 4);
        uint2 v2 = *(const uint2*)(h1 + (size_t)csr[e + 2] * 128 + lane * 4);
        uint2 v3 = *(const uint2*)(h1 + (size_t)csr[e + 3] * 128 + lane * 4);
        uint2 v4 = *(const uint2*)(h1 + (size_t)csr[e + 4] * 128 + lane * 4);
        uint2 v5 = *(const uint2*)(h1 + (size_t)csr[e + 5] * 128 + lane * 4);
        uint2 v6 = *(const uint2*)(h1 + (size_t)csr[e + 6] * 128 + lane * 4);
        uint2 v7 = *(const uint2*)(h1 + (size_t)csr[e + 7] * 128 + lane * 4);
        a0 += ((__uint_as_float(v0.x << 16) + __uint_as_float(v1.x << 16)) +
               (__uint_as_float(v2.x << 16) + __uint_as_float(v3.x << 16))) +
              ((__uint_as_float(v4.x << 16) + __uint_as_float(v5.x << 16)) +
               (__uint_as_float(v6.x << 16) + __uint_as_float(v7.x << 16)));
        a1 += ((__uint_as_float(v0.x & 0xffff0000u) + __uint_as_float(v1.x & 0xffff0000u)) +
               (__uint_as_float(v2.x & 0xffff0000u) + __uint_as_float(v3.x & 0xffff0000u))) +
              ((__uint_as_float(v4.x & 0xffff0000u) + __uint_as_float(v5.x & 0xffff0000u)) +
               (__uint_as_float(v6.x & 0xffff0000u) + __uint_as_float(v7.x & 0xffff0000u)));
        a2 += ((__uint_as_float(v0.y << 16) + __uint_as_float(v1.y << 16)) +
               (__uint_as_float(v2.y << 16) + __uint_as_float(v3.y << 16))) +
              ((__uint_as_float(v4.y << 16) + __uint_as_float(v5.y << 16)) +
               (__uint_as_float(v6.y << 16) + __uint_as_float(v7.y << 16)));
        a3 += ((__uint_as_float(v0.y & 0xffff0000u) + __uint_as_float(v1.y & 0xffff0000u)) +
               (__uint_as_float(v2.y & 0xffff0000u) + __uint_as_float(v3.y & 0xffff0000u))) +
              ((__uint_as_float(v4.y & 0xffff0000u) + __uint_as_float(v5.y & 0xffff0000u)) +
               (__uint_as_float(v6.y & 0xffff0000u) + __uint_as_float(v7.y & 0xffff0000u)));
    }
    for (; e < s1; ++e) {
        uint2 v = *(const uint2*)(h1 + (size_t)csr[e] * 128 + lane * 4);
        a0 += __uint_as_float(v.x << 16);
        a1 += __uint_as_float(v.x & 0xffff0000u);
        a2 += __uint_as_float(v.y << 16);
        a3 += __uint_as_float(v.y & 0xffff0000u);
    }
    float cdi = cd[i];
    float4 bv = *(const float4*)(b1 + lane * 4);
    float4 o;
    o.x = fmaxf(fmaf(a0, cdi, bv.x), 0.f);
    o.y = fmaxf(fmaf(a1, cdi, bv.y), 0.f);
    o.z = fmaxf(fmaf(a2, cdi, bv.z), 0.f);
    o.w = fmaxf(fmaf(a3, cdi, bv.w), 0.f);
    *(float4*)(y + (size_t)i * 128 + lane * 4) = o;
}

// ---- k_h2 (unchanged): A direct; ENTIRE fragment-order B2 (32KB) staged
// once; single barrier, then barrier-free K loop. K=4x32.
__global__ __launch_bounds__(256, 3) void k_h2(
    const float* __restrict__ y,
    const unsigned short* __restrict__ w2tf_hi, const unsigned short* __restrict__ w2tf_lo,
    const float* __restrict__ cs, unsigned short* __restrict__ h2, int N)
{
    constexpr int NT = 4;
    __shared__ __align__(16) short B2h[8192];
    __shared__ __align__(16) short B2l[8192];
    int tid = threadIdx.x;
    int lane = tid & 63, w = tid >> 6;
    int fr = lane & 15, kg = lane >> 4;
    int i0 = blockIdx.x * 128 + w * 32;
    int r0 = i0 + fr;       if (r0 >= N) r0 = N - 1;
    int r1 = i0 + 16 + fr;  if (r1 >= N) r1 = N - 1;
    const float* a0 = y + (size_t)r0 * 128 + kg * 8;
    const float* a1 = y + (size_t)r1 * 128 + kg * 8;

#pragma unroll
    for (int i = 0; i < 4; ++i) {
        *(uint4*)&B2h[(i * 256 + tid) * 8] = *(const uint4*)(w2tf_hi + (size_t)(i * 256 + tid) * 8);
        *(uint4*)&B2l[(i * 256 + tid) * 8] = *(const uint4*)(w2tf_lo + (size_t)(i * 256 + tid) * 8);
    }
    __syncthreads();

    f32x4 acc[2][4];
#pragma unroll
    for (int ri = 0; ri < 2; ++ri)
#pragma unroll
        for (int ci = 0; ci < 4; ++ci) acc[ri][ci] = (f32x4)0.f;

    float4 ar00 = *(const float4*)(a0);
    float4 ar01 = *(const float4*)(a0 + 4);
    float4 ar10 = *(const float4*)(a1);
    float4 ar11 = *(const float4*)(a1 + 4);

    for (int t = 0; t < NT; ++t) {
        short8 ah0, al0, ah1, al1;
        split_f4(ar00, ar01, ah0, al0);
        split_f4(ar10, ar11, ah1, al1);
        if (t + 1 < NT) {
            ar00 = *(const float4*)(a0 + (t + 1) * 32);
            ar01 = *(const float4*)(a0 + (t + 1) * 32 + 4);
            ar10 = *(const float4*)(a1 + (t + 1) * 32);
            ar11 = *(const float4*)(a1 + (t + 1) * 32 + 4);
        }
#pragma unroll
        for (int ci = 0; ci < 4; ++ci) {
            short8 bh = *(const short8*)&B2h[((t * 4 + ci) * 64 + lane) * 8];
            short8 bl = *(const short8*)&B2l[((t * 4 + ci) * 64 + lane) * 8];
            acc[0][ci] = __builtin_amdgcn_mfma_f32_16x16x32_bf16(ah0, bh, acc[0][ci], 0, 0, 0);
            acc[0][ci] = __builtin_amdgcn_mfma_f32_16x16x32_bf16(al0, bh, acc[0][ci], 0, 0, 0);
            acc[0][ci] = __builtin_amdgcn_mfma_f32_16x16x32_bf16(ah0, bl, acc[0][ci], 0, 0, 0);
            acc[1][ci] = __builtin_amdgcn_mfma_f32_16x16x32_bf16(ah1, bh, acc[1][ci], 0, 0, 0);
            acc[1][ci] = __builtin_amdgcn_mfma_f32_16x16x32_bf16(al1, bh, acc[1][ci], 0, 0, 0);
            acc[1][ci] = __builtin_amdgcn_mfma_f32_16x16x32_bf16(ah1, bl, acc[1][ci], 0, 0, 0);
        }
    }

#pragma unroll
    for (int ri = 0; ri < 2; ++ri) {
#pragma unroll
        for (int j = 0; j < 4; ++j) {
            int row = i0 + ri * 16 + kg * 4 + j;
            if (row < N) {
                float scv = cs[row];
#pragma unroll
                for (int ci = 0; ci < 4; ++ci) {
                    h2[(size_t)row * 64 + ci * 16 + fr] = f2bf(scv * acc[ri][ci][j]);
                }
            }
        }
    }
}

// Layer-2 aggregation: out[i] = (sum h2[src_e]) * cd[i] + b2
__global__ __launch_bounds__(256) void k_agg2(
    const unsigned short* __restrict__ h2, const int* __restrict__ rowp,
    const int* __restrict__ csr, const float* __restrict__ cd,
    const float* __restrict__ b2, float* __restrict__ out, int N)
{
    int i = blockIdx.x * 8 + (threadIdx.x >> 5);
    if (i >= N) return;
    int lane = threadIdx.x & 31;
    int s0 = rowp[i], s1 = rowp[i + 1];
    float ax = 0.f, ay = 0.f;
    int e = s0;
    for (; e + 8 <= s1; e += 8) {
        unsigned u0 = *(const unsigned*)(h2 + (size_t)csr[e + 0] * 64 + lane * 2);
        unsigned u1 = *(const unsigned*)(h2 + (size_t)csr[e + 1] * 64 + lane * 2);
        unsigned u2 = *(const unsigned*)(h2 + (size_t)csr[e + 2] * 64 + lane * 2);
        unsigned u3 = *(const unsigned*)(h2 + (size_t)csr[e + 3] * 64 + lane * 2);
        unsigned u4 = *(const unsigned*)(h2 + (size_t)csr[e + 4] * 64 + lane * 2);
        unsigned u5 = *(const unsigned*)(h2 + (size_t)csr[e + 5] * 64 + lane * 2);
        unsigned u6 = *(const unsigned*)(h2 + (size_t)csr[e + 6] * 64 + lane * 2);
        unsigned u7 = *(const unsigned*)(h2 + (size_t)csr[e + 7] * 64 + lane * 2);
        ax += ((__uint_as_float(u0 << 16) + __uint_as_float(u1 << 16)) +
               (__uint_as_float(u2 << 16) + __uint_as_float(u3 << 16))) +
              ((__uint_as_float(u4 << 16) + __uint_as_float(u5 << 16)) +
               (__uint_as_float(u6 << 16) + __uint_as_float(u7 << 16)));
        ay += ((__uint_as_float(u0 & 0xffff0000u) + __uint_as_float(u1 & 0xffff0000u)) +
               (__uint_as_float(u2 & 0xffff0000u) + __uint_as_float(u3 & 0xffff0000u))) +
              ((__uint_as_float(u4 & 0xffff0000u) + __uint_as_float(u5 & 0xffff0000u)) +
               (__uint_as_float(u6 & 0xffff0000u) + __uint_as_float(u7 & 0xffff0000u)));
    }
    for (; e < s1; ++e) {
        unsigned u = *(const unsigned*)(h2 + (size_t)csr[e] * 64 + lane * 2);
        ax += __uint_as_float(u << 16);
        ay += __uint_as_float(u & 0xffff0000u);
    }
    float cdi = cd[i];
    float2 o;
    o.x = fmaf(ax, cdi, b2[lane * 2 + 0]);
    o.y = fmaf(ay, cdi, b2[lane * 2 + 1]);
    *(float2*)(out + (size_t)i * 64 + lane * 2) = o;
}

extern "C" void kernel_launch(void* const* d_in, const int* in_sizes, int n_in,
                              void* d_out, int out_size, void* d_ws, size_t ws_size,
                              hipStream_t stream)
{
    const int* src = (const int*)d_in[0];
    const int* dst = (const int*)d_in[1];
    const float* logits = (const float*)d_in[2];
    const float* features = (const float*)d_in[3];
    const float* projW = (const float*)d_in[4];
    const float* projb = (const float*)d_in[5];
    const float* deg_table = (const float*)d_in[6];
    const float* W1 = (const float*)d_in[7];
    const float* b1 = (const float*)d_in[8];
    const float* W2 = (const float*)d_in[9];
    const float* b2 = (const float*)d_in[10];
    const int E = in_sizes[0];
    const int N = in_sizes[2] / 64;

    char* base = (char*)d_ws;
    size_t off = 0;
    auto alloc = [&](size_t bytes) -> void* {
        void* p = base + off;
        off += (bytes + 255) & ~(size_t)255;
        return p;
    };
    int* ind    = (int*)alloc((size_t)N * 4);
    int* rowp   = (int*)alloc((size_t)(N + 1) * 4);
    int* csr    = (int*)alloc((size_t)E * 4);
    unsigned* ebuf = (unsigned*)alloc((size_t)E * 4);
    unsigned short* sbuf = (unsigned short*)alloc((size_t)E * 2);
    int* didx   = (int*)alloc((size_t)N * 4);
    float* cs   = (float*)alloc((size_t)N * 4);
    float* cd   = (float*)alloc((size_t)N * 4);
    float* WF   = (float*)alloc((size_t)512 * 128 * 4);
    float* cb   = (float*)alloc((size_t)128 * 4);
    int* dcount = (int*)alloc(128 * 4);
    int* scount = (int*)alloc(128 * 4);
    int* dboff  = (int*)alloc(128 * 4);
    int* sboff  = (int*)alloc(128 * 4);
    int* dcur   = (int*)alloc(128 * 4);
    int* scur   = (int*)alloc(128 * 4);
    unsigned short* wtf_hi  = (unsigned short*)alloc((size_t)81920 * 2);
    unsigned short* wtf_lo  = (unsigned short*)alloc((size_t)81920 * 2);
    unsigned short* w2tf_hi = (unsigned short*)alloc((size_t)8192 * 2);
    unsigned short* w2tf_lo = (unsigned short*)alloc((size_t)8192 * 2);
    unsigned short* h1 = (unsigned short*)alloc((size_t)N * 128 * 2);
    float* yb   = (float*)alloc((size_t)N * 128 * 4);
    unsigned short* h2 = h1;   // h1 dead after k_agg1; reuse
    float* outp = (float*)d_out;

    hipMemsetAsync(dcount, 0, 128 * 4, stream);
    hipMemsetAsync(scount, 0, 128 * 4, stream);

    int mb1 = (N + 63) / 64;
    int mb2 = (N + 127) / 128;
    int ebk = (E + 4095) / 4096;
    int nbuck = (N + 1023) / 1024;   // <=128 for N<=131072

    k_bcount<<<ebk, 256, 0, stream>>>(src, dst, E, dcount, scount);
    k_bscan<<<1, 128, 0, stream>>>(dcount, scount, nbuck, E, dboff, sboff, dcur, scur, rowp, N);
    k_scatter2<<<ebk, 256, 0, stream>>>(src, dst, E, dcur, scur, ebuf, sbuf, nbuck);
    k_bucket_dst<<<nbuck, 512, 0, stream>>>(ebuf, dboff, dcount, ind, rowp, csr, N);
    k_bucket_src<<<nbuck, 512, 0, stream>>>(sbuf, sboff, scount, ind, cs, cd, didx, N);
    k_wf<<<257, 256, 0, stream>>>(projW, projb, W1, WF, cb);
    k_wt<<<352, 256, 0, stream>>>(WF, W1, W2, wtf_hi, wtf_lo, w2tf_hi, w2tf_lo);
    k_h1<<<mb1, 256, 0, stream>>>(logits, features, deg_table, didx, wtf_hi, wtf_lo, cb, cs, h1, N);
    k_agg1<<<(N + 7) / 8, 256, 0, stream>>>(h1, rowp, csr, cd, b1, yb, N);
    k_h2<<<mb2, 256, 0, stream>>>(yb, w2tf_hi, w2tf_lo, cs, h2, N);
    k_agg2<<<(N + 7) / 8, 256, 0, stream>>>(h2, rowp, csr, cd, b2, outp, N);
}